// Round 2
// baseline (1953.545 us; speedup 1.0000x reference)
//
#include <hip/hip_runtime.h>
#include <hip/hip_bf16.h>
#include <math.h>

#define N_NODES 50000
#define N_EDGES 800000
#define HID     128
#define NHEAD   8
#define HDIM    16
#define NTYPE   6
#define NLAYER  2

__device__ __forceinline__ float sigmoidf_(float x){ return 1.f/(1.f+__expf(-x)); }
__device__ __forceinline__ float gelu_tanh(float x){
  float x3 = x*x*x;
  return 0.5f*x*(1.f + tanhf(0.7978845608028654f*(x + 0.044715f*x3)));
}

// ---- CSR build --------------------------------------------------------------
__global__ void k_hist(const int* __restrict__ edst, int* __restrict__ deg){
  int e = blockIdx.x*256 + threadIdx.x;
  if (e < N_EDGES) atomicAdd(&deg[edst[e]], 1);
}

__global__ void k_scan(const int* __restrict__ deg, int* __restrict__ rowptr){
  __shared__ int part[256];
  const int chunk = (N_NODES + 255)/256;
  int t = threadIdx.x;
  int beg = t*chunk, end = min(beg+chunk, N_NODES);
  int s = 0;
  for (int i = beg; i < end; ++i) s += deg[i];
  part[t] = s;
  __syncthreads();
  if (t == 0){
    int acc = 0;
    for (int i = 0; i < 256; ++i){ int v = part[i]; part[i] = acc; acc += v; }
    rowptr[N_NODES] = acc;
  }
  __syncthreads();
  int acc = part[t];
  for (int i = beg; i < end; ++i){ rowptr[i] = acc; acc += deg[i]; }
}

__global__ void k_fill(const int* __restrict__ esrc, const int* __restrict__ edst,
                       const int* __restrict__ rowptr, int* __restrict__ cursor,
                       int* __restrict__ csr_src){
  int e = blockIdx.x*256 + threadIdx.x;
  if (e < N_EDGES){
    int d = edst[e];
    int pos = atomicAdd(&cursor[d], 1);
    csr_src[rowptr[d] + pos] = esrc[e];
  }
}

// ---- effective weights: fold rel_att/rel_msg (+rel_pri/sqrt(D)) into Wk/Wv --
__global__ void k_effw(const float* __restrict__ Wk, const float* __restrict__ Wv,
                       const float* __restrict__ A, const float* __restrict__ M,
                       const float* __restrict__ pri, float* __restrict__ WkA,
                       float* __restrict__ WvM){
  int idx = blockIdx.x*256 + threadIdx.x;
  if (idx >= NTYPE*HID*HID) return;
  int hf = idx & (HID-1);
  int hh = hf >> 4, f = hf & 15;
  int base = idx - hf;                       // t*HID*HID + i*HID
  const float* a  = A + hh*HDIM*HDIM;
  const float* m  = M + hh*HDIM*HDIM;
  const float* wk = Wk + base + hh*HDIM;
  const float* wv = Wv + base + hh*HDIM;
  float sa = 0.f, sm = 0.f;
  #pragma unroll
  for (int d = 0; d < HDIM; ++d){ sa += wk[d]*a[d*HDIM+f]; sm += wv[d]*m[d*HDIM+f]; }
  WkA[idx] = sa * pri[hh] * 0.25f;           // 1/sqrt(16) = 0.25
  WvM[idx] = sm;
}

// ---- projections: h = hidden + xnorm@Wpos; q = h@Wq[t]; kA = h@WkA[t]; vm = h@WvM[t]
__global__ void k_proj(const float* __restrict__ hidden, const float* __restrict__ xnorm,
                       const int* __restrict__ ntype, const float* __restrict__ Wpos,
                       const float* __restrict__ Wq, const float* __restrict__ WkA,
                       const float* __restrict__ WvM,
                       float* __restrict__ qout, float* __restrict__ kaout,
                       float* __restrict__ vmout){
  __shared__ float hs[4][HID];
  int wid = threadIdx.x >> 6, lane = threadIdx.x & 63;
  int n = blockIdx.x*4 + wid;                // N_NODES % 4 == 0
  int t = ntype[n];
  int j = 2*lane;
  float xa0 = xnorm[2*n], xa1 = xnorm[2*n+1];
  float2 hv = *(const float2*)(hidden + (size_t)n*HID + j);
  float h0 = hv.x + xa0*Wpos[j]     + xa1*Wpos[HID + j];
  float h1 = hv.y + xa0*Wpos[j + 1] + xa1*Wpos[HID + j + 1];
  hs[wid][j] = h0; hs[wid][j+1] = h1;
  __syncthreads();
  const float* wq = Wq  + (size_t)t*HID*HID;
  const float* wk = WkA + (size_t)t*HID*HID;
  const float* wv = WvM + (size_t)t*HID*HID;
  float q0=0,q1=0,k0=0,k1=0,v0=0,v1=0;
  for (int i = 0; i < HID; ++i){
    float hi = hs[wid][i];
    float2 a = *(const float2*)(wq + i*HID + j);
    float2 b = *(const float2*)(wk + i*HID + j);
    float2 c = *(const float2*)(wv + i*HID + j);
    q0 = fmaf(hi, a.x, q0); q1 = fmaf(hi, a.y, q1);
    k0 = fmaf(hi, b.x, k0); k1 = fmaf(hi, b.y, k1);
    v0 = fmaf(hi, c.x, v0); v1 = fmaf(hi, c.y, v1);
  }
  size_t o = (size_t)n*HID + j;
  *(float2*)(qout  + o) = make_float2(q0, q1);
  *(float2*)(kaout + o) = make_float2(k0, k1);
  *(float2*)(vmout + o) = make_float2(v0, v1);
}

// ---- fused attention (online softmax over CSR) + gelu + Wa + epilogue ------
__global__ void k_attn(const int* __restrict__ ntype, const int* __restrict__ rowptr,
                       const int* __restrict__ csr_src, const float* __restrict__ q,
                       const float* __restrict__ kA, const float* __restrict__ vm,
                       const float* __restrict__ xnorm, const float* __restrict__ Wpos,
                       const float* __restrict__ Wa,
                       const float* __restrict__ skip, const float* __restrict__ wpri,
                       float* __restrict__ hidden, float* __restrict__ cn,
                       float* __restrict__ pri, int last){
  __shared__ float ts[4][HID];
  int wid = threadIdx.x >> 6, lane = threadIdx.x & 63;
  int n = blockIdx.x*4 + wid;
  int t = ntype[n];
  int j = 2*lane;                            // lane covers elements j, j+1 -> head j/16
  int beg = rowptr[n], end = rowptr[n+1];
  float2 qv = *(const float2*)(q + (size_t)n*HID + j);
  float m = -INFINITY, s = 0.f, a0 = 0.f, a1 = 0.f;
  for (int e = beg; e < end; ++e){
    int src = csr_src[e];
    float2 kv = *(const float2*)(kA + (size_t)src*HID + j);
    float2 vv = *(const float2*)(vm + (size_t)src*HID + j);
    float p = kv.x*qv.x + kv.y*qv.y;
    p += __shfl_xor(p, 1); p += __shfl_xor(p, 2); p += __shfl_xor(p, 4);  // 8-lane head reduce
    float mn  = fmaxf(m, p);
    float fct = __expf(m - mn);              // first iter: exp(-inf)=0
    float w   = __expf(p - mn);
    s  = s*fct + w;
    a0 = a0*fct + w*vv.x;
    a1 = a1*fct + w*vv.y;
    m = mn;
  }
  float inv = 1.f/(s + 1e-16f);              // deg==0 -> agg = 0, matches reference
  float g0 = gelu_tanh(a0*inv), g1 = gelu_tanh(a1*inv);
  ts[wid][j] = g0; ts[wid][j+1] = g1;
  __syncthreads();
  const float* wa = Wa + (size_t)t*HID*HID;
  float o0 = 0.f, o1 = 0.f;
  for (int i = 0; i < HID; ++i){
    float ti = ts[wid][i];
    float2 wv2 = *(const float2*)(wa + i*HID + j);
    o0 = fmaf(ti, wv2.x, o0); o1 = fmaf(ti, wv2.y, o1);
  }
  // recompute h = hidden + xnorm@Wpos for the skip mix (cheap; saves the h buffer)
  float xa0 = xnorm[2*n], xa1 = xnorm[2*n+1];
  size_t o = (size_t)n*HID + j;
  float2 hv = *(const float2*)(hidden + o);
  float h0 = hv.x + xa0*Wpos[j]     + xa1*Wpos[HID + j];
  float h1 = hv.y + xa0*Wpos[j + 1] + xa1*Wpos[HID + j + 1];
  float sk = sigmoidf_(skip[t]);
  float hg0 = sk*o0 + (1.f - sk)*h0;
  float hg1 = sk*o1 + (1.f - sk)*h1;
  if (last){
    float pp = hg0*wpri[j] + hg1*wpri[j+1];
    #pragma unroll
    for (int d2 = 1; d2 < 64; d2 <<= 1) pp += __shfl_xor(pp, d2);
    if (lane == 0) pri[n] = sigmoidf_(pp);
  }
  float2 cv = *(const float2*)(cn + o);
  float c0 = hg0 + cv.x, c1 = hg1 + cv.y;
  *(float2*)(cn + o) = make_float2(c0, c1);
  *(float2*)(hidden + o) = make_float2(hv.x + tanhf(c0), hv.y + tanhf(c1));
}

// ---- launcher ---------------------------------------------------------------
extern "C" void kernel_launch(void* const* d_in, const int* in_sizes, int n_in,
                              void* d_out, int out_size, void* d_ws, size_t ws_size,
                              hipStream_t stream){
  const float* hidden_in = (const float*)d_in[0];
  const float* cn_in     = (const float*)d_in[1];
  const float* xnorm     = (const float*)d_in[2];
  const int*   ntype     = (const int*)d_in[3];
  const int*   esrc      = (const int*)d_in[4];
  const int*   edst      = (const int*)d_in[5];
  const float* Wpos      = (const float*)d_in[6];   // [L][2][H]
  const float* Wk        = (const float*)d_in[7];   // [L][T][H][H]
  const float* Wq        = (const float*)d_in[8];
  const float* Wv        = (const float*)d_in[9];
  const float* Wa        = (const float*)d_in[10];
  const float* Ratt      = (const float*)d_in[11];  // [L][NH][D][D]
  const float* Rmsg      = (const float*)d_in[12];
  const float* Rpri      = (const float*)d_in[13];  // [L][NH]
  const float* Skip      = (const float*)d_in[14];  // [L][T]
  const float* Wpri      = (const float*)d_in[15];  // [L][H]

  char* ws = (char*)d_ws;
  size_t off = 0;
  auto alloc = [&](size_t bytes)->void*{ void* p = ws + off; off += (bytes + 255) & ~(size_t)255; return p; };
  float* q    = (float*)alloc((size_t)N_NODES*HID*4);
  float* kA   = (float*)alloc((size_t)N_NODES*HID*4);
  float* vm   = (float*)alloc((size_t)N_NODES*HID*4);
  float* WkA  = (float*)alloc((size_t)NTYPE*HID*HID*4);
  float* WvM  = (float*)alloc((size_t)NTYPE*HID*HID*4);
  int* deg    = (int*)alloc((size_t)N_NODES*4);
  int* rowptr = (int*)alloc((size_t)(N_NODES+1)*4);
  int* cursor = (int*)alloc((size_t)N_NODES*4);
  int* csr    = (int*)alloc((size_t)N_EDGES*4);

  float* out_hidden = (float*)d_out;
  float* out_cn     = out_hidden + (size_t)N_NODES*HID;
  float* out_pri    = out_cn     + (size_t)N_NODES*HID;

  hipMemsetAsync(deg,    0, (size_t)N_NODES*4, stream);
  hipMemsetAsync(cursor, 0, (size_t)N_NODES*4, stream);
  k_hist<<<(N_EDGES+255)/256, 256, 0, stream>>>(edst, deg);
  k_scan<<<1, 256, 0, stream>>>(deg, rowptr);
  k_fill<<<(N_EDGES+255)/256, 256, 0, stream>>>(esrc, edst, rowptr, cursor, csr);

  hipMemcpyAsync(out_hidden, hidden_in, (size_t)N_NODES*HID*4, hipMemcpyDeviceToDevice, stream);
  hipMemcpyAsync(out_cn,     cn_in,     (size_t)N_NODES*HID*4, hipMemcpyDeviceToDevice, stream);

  for (int l = 0; l < NLAYER; ++l){
    const float* Wpos_l = Wpos + (size_t)l*2*HID;
    const float* Wk_l   = Wk   + (size_t)l*NTYPE*HID*HID;
    const float* Wq_l   = Wq   + (size_t)l*NTYPE*HID*HID;
    const float* Wv_l   = Wv   + (size_t)l*NTYPE*HID*HID;
    const float* Wa_l   = Wa   + (size_t)l*NTYPE*HID*HID;
    const float* Ratt_l = Ratt + (size_t)l*NHEAD*HDIM*HDIM;
    const float* Rmsg_l = Rmsg + (size_t)l*NHEAD*HDIM*HDIM;
    const float* Rpri_l = Rpri + (size_t)l*NHEAD;
    const float* Skip_l = Skip + (size_t)l*NTYPE;
    const float* Wpri_l = Wpri + (size_t)l*HID;

    k_effw<<<(NTYPE*HID*HID+255)/256, 256, 0, stream>>>(Wk_l, Wv_l, Ratt_l, Rmsg_l, Rpri_l, WkA, WvM);
    k_proj<<<N_NODES/4, 256, 0, stream>>>(out_hidden, xnorm, ntype, Wpos_l, Wq_l, WkA, WvM,
                                          q, kA, vm);
    k_attn<<<N_NODES/4, 256, 0, stream>>>(ntype, rowptr, csr, q, kA, vm, xnorm, Wpos_l, Wa_l,
                                          Skip_l, Wpri_l, out_hidden, out_cn, out_pri,
                                          l == NLAYER-1);
  }
}

// Round 4
// 1256.745 us; speedup vs baseline: 1.5544x; 1.5544x over previous
//
#include <hip/hip_runtime.h>
#include <hip/hip_bf16.h>
#include <math.h>

#define N_NODES 50000
#define N_EDGES 800000
#define HID     128
#define NHEAD   8
#define HDIM    16
#define NTYPE   6
#define NLAYER  2
#define TILE_N  64
#define PROJ_BLOCKS_PER_TYPE 782   // ceil(50000/64) worst case, one type owns all nodes

__device__ __forceinline__ float sigmoidf_(float x){ return 1.f/(1.f+__expf(-x)); }
__device__ __forceinline__ float gelu_tanh(float x){
  float x3 = x*x*x;
  return 0.5f*x*(1.f + tanhf(0.7978845608028654f*(x + 0.044715f*x3)));
}

// ---- CSR build --------------------------------------------------------------
__global__ void k_hist(const int* __restrict__ edst, int* __restrict__ deg){
  int e = blockIdx.x*256 + threadIdx.x;
  if (e < N_EDGES) atomicAdd(&deg[edst[e]], 1);
}

__global__ void k_scan(const int* __restrict__ deg, int* __restrict__ rowptr){
  __shared__ int part[256];
  const int chunk = (N_NODES + 255)/256;
  int t = threadIdx.x;
  int beg = t*chunk, end = min(beg+chunk, N_NODES);
  int s = 0;
  for (int i = beg; i < end; ++i) s += deg[i];
  part[t] = s;
  __syncthreads();
  if (t == 0){
    int acc = 0;
    for (int i = 0; i < 256; ++i){ int v = part[i]; part[i] = acc; acc += v; }
    rowptr[N_NODES] = acc;
  }
  __syncthreads();
  int acc = part[t];
  for (int i = beg; i < end; ++i){ rowptr[i] = acc; acc += deg[i]; }
}

__global__ void k_fill(const int* __restrict__ esrc, const int* __restrict__ edst,
                       const int* __restrict__ rowptr, int* __restrict__ cursor,
                       int* __restrict__ csr_src){
  int e = blockIdx.x*256 + threadIdx.x;
  if (e < N_EDGES){
    int d = edst[e];
    int pos = atomicAdd(&cursor[d], 1);
    csr_src[rowptr[d] + pos] = esrc[e];
  }
}

// ---- type bucketing ---------------------------------------------------------
__global__ void k_thist(const int* __restrict__ ntype, int* __restrict__ tcount){
  int n = blockIdx.x*256 + threadIdx.x;
  if (n < N_NODES) atomicAdd(&tcount[ntype[n]], 1);
}

__global__ void k_tscan(const int* __restrict__ tcount, int* __restrict__ toffset){
  if (threadIdx.x == 0){
    int acc = 0;
    for (int i = 0; i < NTYPE; ++i){ toffset[i] = acc; acc += tcount[i]; }
  }
}

__global__ void k_tfill(const int* __restrict__ ntype, const int* __restrict__ toffset,
                        int* __restrict__ tcursor, int* __restrict__ tnodes){
  int n = blockIdx.x*256 + threadIdx.x;
  if (n < N_NODES){
    int t = ntype[n];
    int pos = atomicAdd(&tcursor[t], 1);
    tnodes[toffset[t] + pos] = n;
  }
}

// ---- effective weights: fold rel_att/rel_msg (+rel_pri/sqrt(D)) into Wk/Wv --
__global__ void k_effw(const float* __restrict__ Wk, const float* __restrict__ Wv,
                       const float* __restrict__ A, const float* __restrict__ M,
                       const float* __restrict__ pri, float* __restrict__ WkA,
                       float* __restrict__ WvM){
  int idx = blockIdx.x*256 + threadIdx.x;
  if (idx >= NTYPE*HID*HID) return;
  int hf = idx & (HID-1);
  int hh = hf >> 4, f = hf & 15;
  int base = idx - hf;
  const float* a  = A + hh*HDIM*HDIM;
  const float* m  = M + hh*HDIM*HDIM;
  const float* wk = Wk + base + hh*HDIM;
  const float* wv = Wv + base + hh*HDIM;
  float sa = 0.f, sm = 0.f;
  #pragma unroll
  for (int d = 0; d < HDIM; ++d){ sa += wk[d]*a[d*HDIM+f]; sm += wv[d]*m[d*HDIM+f]; }
  WkA[idx] = sa * pri[hh] * 0.25f;
  WvM[idx] = sm;
}

// ---- type-bucketed projection GEMM: [64 nodes] x [128] @ W[128][128] x3 ----
// q -> qbuf[N][128]; kA,vm interleaved -> kv[N][256] (kA at +0, vm at +128)
__global__ void __launch_bounds__(256)
k_proj_t(const float* __restrict__ hidden, const float* __restrict__ xnorm,
         const int* __restrict__ tnodes, const int* __restrict__ tcount,
         const int* __restrict__ toffset, const float* __restrict__ Wpos,
         const float* __restrict__ Wq, const float* __restrict__ WkA,
         const float* __restrict__ WvM, float* __restrict__ qout,
         float* __restrict__ kvout){
  int ty   = blockIdx.x / PROJ_BLOCKS_PER_TYPE;
  int tile = blockIdx.x % PROJ_BLOCKS_PER_TYPE;
  int cnt  = tcount[ty];
  int base = tile*TILE_N;
  if (base >= cnt) return;
  __shared__ float hs[TILE_N][HID];
  __shared__ int nl[TILE_N];
  int t  = threadIdx.x;
  int c  = t & 31;          // col tile: cols 4c..4c+3
  int rt = t >> 5;          // node tile: nodes rt*8..rt*8+7
  int off = toffset[ty];
  float4 w0 = *(const float4*)(Wpos + 4*c);
  float4 w1 = *(const float4*)(Wpos + HID + 4*c);
  #pragma unroll
  for (int pass = 0; pass < 8; ++pass){
    int r = pass*8 + rt;
    int node = -1;
    float4 hv = make_float4(0.f,0.f,0.f,0.f);
    if (base + r < cnt){
      node = tnodes[off + base + r];
      float xa0 = xnorm[2*node], xa1 = xnorm[2*node+1];
      float4 hd = *(const float4*)(hidden + (size_t)node*HID + 4*c);
      hv.x = hd.x + xa0*w0.x + xa1*w1.x;
      hv.y = hd.y + xa0*w0.y + xa1*w1.y;
      hv.z = hd.z + xa0*w0.z + xa1*w1.z;
      hv.w = hd.w + xa0*w0.w + xa1*w1.w;
    }
    if (c == 0) nl[r] = node;
    *(float4*)&hs[r][4*c] = hv;
  }
  __syncthreads();

  const float* mats[3] = {Wq + (size_t)ty*HID*HID, WkA + (size_t)ty*HID*HID,
                          WvM + (size_t)ty*HID*HID};
  #pragma unroll 1
  for (int m = 0; m < 3; ++m){
    const float* W = mats[m];
    float4 acc[8];
    #pragma unroll
    for (int r = 0; r < 8; ++r) acc[r] = make_float4(0.f,0.f,0.f,0.f);
    for (int k0 = 0; k0 < HID; k0 += 4){
      float4 hr[8];
      #pragma unroll
      for (int r = 0; r < 8; ++r) hr[r] = *(const float4*)&hs[rt*8+r][k0];
      #pragma unroll
      for (int kk = 0; kk < 4; ++kk){
        float4 w = *(const float4*)(W + (size_t)(k0+kk)*HID + 4*c);
        #pragma unroll
        for (int r = 0; r < 8; ++r){
          float hvv = ((const float*)&hr[r])[kk];
          acc[r].x = fmaf(hvv, w.x, acc[r].x);
          acc[r].y = fmaf(hvv, w.y, acc[r].y);
          acc[r].z = fmaf(hvv, w.z, acc[r].z);
          acc[r].w = fmaf(hvv, w.w, acc[r].w);
        }
      }
    }
    #pragma unroll
    for (int r = 0; r < 8; ++r){
      int node = nl[rt*8+r];
      if (node >= 0){
        if (m == 0)      *(float4*)(qout  + (size_t)node*HID + 4*c)       = acc[r];
        else if (m == 1) *(float4*)(kvout + (size_t)node*2*HID + 4*c)     = acc[r];
        else             *(float4*)(kvout + (size_t)node*2*HID + HID + 4*c) = acc[r];
      }
    }
  }
}

// ---- edge attention: online softmax over CSR, writes trans = gelu(agg) -----
// trans aliases the q buffer (each warp reads q[n] fully before writing).
__global__ void k_edge(const int* __restrict__ rowptr, const int* __restrict__ csr_src,
                       const float* __restrict__ q, const float* __restrict__ kv,
                       float* __restrict__ trans){
  int wid = threadIdx.x >> 6, lane = threadIdx.x & 63;
  int n = blockIdx.x*4 + wid;
  int j = 2*lane;
  int beg = rowptr[n], end = rowptr[n+1];
  float2 qv = *(const float2*)(q + (size_t)n*HID + j);
  float m = -INFINITY, s = 0.f, a0 = 0.f, a1 = 0.f;
  int e = beg;
  for (; e + 2 <= end; e += 2){
    int s0 = csr_src[e], s1 = csr_src[e+1];
    const float* r0 = kv + (size_t)s0*2*HID;
    const float* r1 = kv + (size_t)s1*2*HID;
    float2 k0 = *(const float2*)(r0 + j);
    float2 v0 = *(const float2*)(r0 + HID + j);
    float2 k1 = *(const float2*)(r1 + j);
    float2 v1 = *(const float2*)(r1 + HID + j);
    float p0 = k0.x*qv.x + k0.y*qv.y;
    float p1 = k1.x*qv.x + k1.y*qv.y;
    p0 += __shfl_xor(p0,1); p0 += __shfl_xor(p0,2); p0 += __shfl_xor(p0,4);
    p1 += __shfl_xor(p1,1); p1 += __shfl_xor(p1,2); p1 += __shfl_xor(p1,4);
    float mn  = fmaxf(m, fmaxf(p0, p1));
    float fct = __expf(m - mn);
    float w0  = __expf(p0 - mn), w1 = __expf(p1 - mn);
    s  = s*fct + w0 + w1;
    a0 = a0*fct + w0*v0.x + w1*v1.x;
    a1 = a1*fct + w0*v0.y + w1*v1.y;
    m = mn;
  }
  if (e < end){
    int s0 = csr_src[e];
    const float* r0 = kv + (size_t)s0*2*HID;
    float2 k0 = *(const float2*)(r0 + j);
    float2 v0 = *(const float2*)(r0 + HID + j);
    float p0 = k0.x*qv.x + k0.y*qv.y;
    p0 += __shfl_xor(p0,1); p0 += __shfl_xor(p0,2); p0 += __shfl_xor(p0,4);
    float mn  = fmaxf(m, p0);
    float fct = __expf(m - mn);
    float w0  = __expf(p0 - mn);
    s  = s*fct + w0;
    a0 = a0*fct + w0*v0.x;
    a1 = a1*fct + w0*v0.y;
  }
  float inv = 1.f/(s + 1e-16f);
  *(float2*)(trans + (size_t)n*HID + j) =
      make_float2(gelu_tanh(a0*inv), gelu_tanh(a1*inv));
}

// ---- type-bucketed output GEMM (Wa) + fused epilogue -----------------------
__global__ void __launch_bounds__(256)
k_post_t(const float* __restrict__ trans, const float* __restrict__ xnorm,
         const int* __restrict__ tnodes, const int* __restrict__ tcount,
         const int* __restrict__ toffset, const float* __restrict__ Wpos,
         const float* __restrict__ Wa, const float* __restrict__ skip,
         const float* __restrict__ wpri, float* __restrict__ hidden,
         float* __restrict__ cn, float* __restrict__ pri, int last){
  int ty   = blockIdx.x / PROJ_BLOCKS_PER_TYPE;
  int tile = blockIdx.x % PROJ_BLOCKS_PER_TYPE;
  int cnt  = tcount[ty];
  int base = tile*TILE_N;
  if (base >= cnt) return;
  __shared__ float ts[TILE_N][HID];
  __shared__ int nl[TILE_N];
  int t  = threadIdx.x;
  int c  = t & 31;
  int rt = t >> 5;
  int off = toffset[ty];
  #pragma unroll
  for (int pass = 0; pass < 8; ++pass){
    int r = pass*8 + rt;
    int node = -1;
    float4 tv = make_float4(0.f,0.f,0.f,0.f);
    if (base + r < cnt){
      node = tnodes[off + base + r];
      tv = *(const float4*)(trans + (size_t)node*HID + 4*c);
    }
    if (c == 0) nl[r] = node;
    *(float4*)&ts[r][4*c] = tv;
  }
  __syncthreads();

  const float* W = Wa + (size_t)ty*HID*HID;
  float4 acc[8];
  #pragma unroll
  for (int r = 0; r < 8; ++r) acc[r] = make_float4(0.f,0.f,0.f,0.f);
  for (int k0 = 0; k0 < HID; k0 += 4){
    float4 hr[8];
    #pragma unroll
    for (int r = 0; r < 8; ++r) hr[r] = *(const float4*)&ts[rt*8+r][k0];
    #pragma unroll
    for (int kk = 0; kk < 4; ++kk){
      float4 w = *(const float4*)(W + (size_t)(k0+kk)*HID + 4*c);
      #pragma unroll
      for (int r = 0; r < 8; ++r){
        float hvv = ((const float*)&hr[r])[kk];
        acc[r].x = fmaf(hvv, w.x, acc[r].x);
        acc[r].y = fmaf(hvv, w.y, acc[r].y);
        acc[r].z = fmaf(hvv, w.z, acc[r].z);
        acc[r].w = fmaf(hvv, w.w, acc[r].w);
      }
    }
  }

  float sk = sigmoidf_(skip[ty]);
  float4 w0 = *(const float4*)(Wpos + 4*c);
  float4 w1 = *(const float4*)(Wpos + HID + 4*c);
  float4 wp = *(const float4*)(wpri + 4*c);
  float ppv[8];
  #pragma unroll
  for (int r = 0; r < 8; ++r){
    int node = nl[rt*8+r];
    ppv[r] = 0.f;
    if (node < 0) continue;
    size_t o = (size_t)node*HID + 4*c;
    float xa0 = xnorm[2*node], xa1 = xnorm[2*node+1];
    float4 hd = *(const float4*)(hidden + o);
    float4 cv = *(const float4*)(cn + o);
    float h0 = hd.x + xa0*w0.x + xa1*w1.x;
    float h1 = hd.y + xa0*w0.y + xa1*w1.y;
    float h2 = hd.z + xa0*w0.z + xa1*w1.z;
    float h3 = hd.w + xa0*w0.w + xa1*w1.w;
    float hg0 = sk*acc[r].x + (1.f - sk)*h0;
    float hg1 = sk*acc[r].y + (1.f - sk)*h1;
    float hg2 = sk*acc[r].z + (1.f - sk)*h2;
    float hg3 = sk*acc[r].w + (1.f - sk)*h3;
    ppv[r] = hg0*wp.x + hg1*wp.y + hg2*wp.z + hg3*wp.w;
    float c0 = hg0 + cv.x, c1 = hg1 + cv.y, c2 = hg2 + cv.z, c3 = hg3 + cv.w;
    *(float4*)(cn + o) = make_float4(c0, c1, c2, c3);
    *(float4*)(hidden + o) = make_float4(hd.x + tanhf(c0), hd.y + tanhf(c1),
                                         hd.z + tanhf(c2), hd.w + tanhf(c3));
  }
  if (last){
    #pragma unroll
    for (int r = 0; r < 8; ++r){
      float pp = ppv[r];
      pp += __shfl_xor(pp, 1); pp += __shfl_xor(pp, 2); pp += __shfl_xor(pp, 4);
      pp += __shfl_xor(pp, 8); pp += __shfl_xor(pp, 16);
      ppv[r] = pp;
    }
    if (c == 0){
      #pragma unroll
      for (int r = 0; r < 8; ++r){
        int node = nl[rt*8+r];
        if (node >= 0) pri[node] = sigmoidf_(ppv[r]);
      }
    }
  }
}

// ---- launcher ---------------------------------------------------------------
extern "C" void kernel_launch(void* const* d_in, const int* in_sizes, int n_in,
                              void* d_out, int out_size, void* d_ws, size_t ws_size,
                              hipStream_t stream){
  const float* hidden_in = (const float*)d_in[0];
  const float* cn_in     = (const float*)d_in[1];
  const float* xnorm     = (const float*)d_in[2];
  const int*   ntype     = (const int*)d_in[3];
  const int*   esrc      = (const int*)d_in[4];
  const int*   edst      = (const int*)d_in[5];
  const float* Wpos      = (const float*)d_in[6];
  const float* Wk        = (const float*)d_in[7];
  const float* Wq        = (const float*)d_in[8];
  const float* Wv        = (const float*)d_in[9];
  const float* Wa        = (const float*)d_in[10];
  const float* Ratt      = (const float*)d_in[11];
  const float* Rmsg      = (const float*)d_in[12];
  const float* Rpri      = (const float*)d_in[13];
  const float* Skip      = (const float*)d_in[14];
  const float* Wpri      = (const float*)d_in[15];

  char* ws = (char*)d_ws;
  size_t off = 0;
  auto alloc = [&](size_t bytes)->void*{ void* p = ws + off; off += (bytes + 255) & ~(size_t)255; return p; };
  float* qbuf  = (float*)alloc((size_t)N_NODES*HID*4);     // q, then trans (aliased)
  float* kvbuf = (float*)alloc((size_t)N_NODES*2*HID*4);   // kA | vm interleaved
  float* WkA   = (float*)alloc((size_t)NTYPE*HID*HID*4);
  float* WvM   = (float*)alloc((size_t)NTYPE*HID*HID*4);
  int* deg     = (int*)alloc((size_t)N_NODES*4);
  int* rowptr  = (int*)alloc((size_t)(N_NODES+1)*4);
  int* cursor  = (int*)alloc((size_t)N_NODES*4);
  int* csr     = (int*)alloc((size_t)N_EDGES*4);
  int* tcount  = (int*)alloc(8*4);
  int* toffset = (int*)alloc(8*4);
  int* tcursor = (int*)alloc(8*4);
  int* tnodes  = (int*)alloc((size_t)N_NODES*4);

  float* out_hidden = (float*)d_out;
  float* out_cn     = out_hidden + (size_t)N_NODES*HID;
  float* out_pri    = out_cn     + (size_t)N_NODES*HID;

  hipMemsetAsync(deg,     0, (size_t)N_NODES*4, stream);
  hipMemsetAsync(cursor,  0, (size_t)N_NODES*4, stream);
  hipMemsetAsync(tcount,  0, 8*4, stream);
  hipMemsetAsync(tcursor, 0, 8*4, stream);
  k_hist<<<(N_EDGES+255)/256, 256, 0, stream>>>(edst, deg);
  k_scan<<<1, 256, 0, stream>>>(deg, rowptr);
  k_fill<<<(N_EDGES+255)/256, 256, 0, stream>>>(esrc, edst, rowptr, cursor, csr);
  k_thist<<<(N_NODES+255)/256, 256, 0, stream>>>(ntype, tcount);
  k_tscan<<<1, 64, 0, stream>>>(tcount, toffset);
  k_tfill<<<(N_NODES+255)/256, 256, 0, stream>>>(ntype, toffset, tcursor, tnodes);

  hipMemcpyAsync(out_hidden, hidden_in, (size_t)N_NODES*HID*4, hipMemcpyDeviceToDevice, stream);
  hipMemcpyAsync(out_cn,     cn_in,     (size_t)N_NODES*HID*4, hipMemcpyDeviceToDevice, stream);

  const int proj_grid = NTYPE * PROJ_BLOCKS_PER_TYPE;
  for (int l = 0; l < NLAYER; ++l){
    const float* Wpos_l = Wpos + (size_t)l*2*HID;
    const float* Wk_l   = Wk   + (size_t)l*NTYPE*HID*HID;
    const float* Wq_l   = Wq   + (size_t)l*NTYPE*HID*HID;
    const float* Wv_l   = Wv   + (size_t)l*NTYPE*HID*HID;
    const float* Wa_l   = Wa   + (size_t)l*NTYPE*HID*HID;
    const float* Ratt_l = Ratt + (size_t)l*NHEAD*HDIM*HDIM;
    const float* Rmsg_l = Rmsg + (size_t)l*NHEAD*HDIM*HDIM;
    const float* Rpri_l = Rpri + (size_t)l*NHEAD;
    const float* Skip_l = Skip + (size_t)l*NTYPE;
    const float* Wpri_l = Wpri + (size_t)l*HID;

    k_effw<<<(NTYPE*HID*HID+255)/256, 256, 0, stream>>>(Wk_l, Wv_l, Ratt_l, Rmsg_l, Rpri_l, WkA, WvM);
    k_proj_t<<<proj_grid, 256, 0, stream>>>(out_hidden, xnorm, tnodes, tcount, toffset,
                                            Wpos_l, Wq_l, WkA, WvM, qbuf, kvbuf);
    k_edge<<<N_NODES/4, 256, 0, stream>>>(rowptr, csr, qbuf, kvbuf, qbuf);
    k_post_t<<<proj_grid, 256, 0, stream>>>(qbuf, xnorm, tnodes, tcount, toffset,
                                            Wpos_l, Wa_l, Skip_l, Wpri_l,
                                            out_hidden, out_cn, out_pri, l == NLAYER-1);
  }
}

// Round 5
// 837.963 us; speedup vs baseline: 2.3313x; 1.4998x over previous
//
#include <hip/hip_runtime.h>
#include <hip/hip_bf16.h>
#include <math.h>

#define N_NODES 50000
#define N_EDGES 800000
#define HID     128
#define NHEAD   8
#define HDIM    16
#define NTYPE   6
#define NLAYER  2
#define TILE_N  64
#define PROJ_BLOCKS_PER_TYPE 782   // ceil(50000/64) worst case, one type owns all nodes

__device__ __forceinline__ float sigmoidf_(float x){ return 1.f/(1.f+__expf(-x)); }
__device__ __forceinline__ float gelu_tanh(float x){
  float x3 = x*x*x;
  return 0.5f*x*(1.f + tanhf(0.7978845608028654f*(x + 0.044715f*x3)));
}

// ---- CSR build --------------------------------------------------------------
__global__ void k_hist(const int* __restrict__ edst, int* __restrict__ deg){
  int e = blockIdx.x*256 + threadIdx.x;
  if (e < N_EDGES) atomicAdd(&deg[edst[e]], 1);
}

__global__ void k_scan(const int* __restrict__ deg, int* __restrict__ rowptr){
  __shared__ int part[256];
  const int chunk = (N_NODES + 255)/256;
  int t = threadIdx.x;
  int beg = t*chunk, end = min(beg+chunk, N_NODES);
  int s = 0;
  for (int i = beg; i < end; ++i) s += deg[i];
  part[t] = s;
  __syncthreads();
  if (t == 0){
    int acc = 0;
    for (int i = 0; i < 256; ++i){ int v = part[i]; part[i] = acc; acc += v; }
    rowptr[N_NODES] = acc;
  }
  __syncthreads();
  int acc = part[t];
  for (int i = beg; i < end; ++i){ rowptr[i] = acc; acc += deg[i]; }
}

__global__ void k_fill(const int* __restrict__ esrc, const int* __restrict__ edst,
                       const int* __restrict__ rowptr, int* __restrict__ cursor,
                       int* __restrict__ csr_src){
  int e = blockIdx.x*256 + threadIdx.x;
  if (e < N_EDGES){
    int d = edst[e];
    int pos = atomicAdd(&cursor[d], 1);
    csr_src[rowptr[d] + pos] = esrc[e];
  }
}

// ---- type bucketing (block-aggregated: ~6 global atomics per block) --------
__global__ void k_thist(const int* __restrict__ ntype, int* __restrict__ tcount){
  __shared__ int c[NTYPE];
  int t = threadIdx.x;
  if (t < NTYPE) c[t] = 0;
  __syncthreads();
  int n = blockIdx.x*256 + t;
  if (n < N_NODES) atomicAdd(&c[ntype[n]], 1);
  __syncthreads();
  if (t < NTYPE && c[t] > 0) atomicAdd(&tcount[t], c[t]);
}

__global__ void k_tscan(const int* __restrict__ tcount, int* __restrict__ toffset){
  if (threadIdx.x == 0){
    int acc = 0;
    for (int i = 0; i < NTYPE; ++i){ toffset[i] = acc; acc += tcount[i]; }
  }
}

__global__ void k_tfill(const int* __restrict__ ntype, const int* __restrict__ toffset,
                        int* __restrict__ tcursor, int* __restrict__ tnodes){
  __shared__ int c[NTYPE], base[NTYPE];
  int t = threadIdx.x;
  if (t < NTYPE) c[t] = 0;
  __syncthreads();
  int n = blockIdx.x*256 + t;
  int ty = 0, rank = 0;
  bool valid = (n < N_NODES);
  if (valid){ ty = ntype[n]; rank = atomicAdd(&c[ty], 1); }
  __syncthreads();
  if (t < NTYPE && c[t] > 0) base[t] = atomicAdd(&tcursor[t], c[t]);
  __syncthreads();
  if (valid) tnodes[toffset[ty] + base[ty] + rank] = n;
}

// ---- effective weights: fold rel_att/rel_msg (+rel_pri/sqrt(D)) into Wk/Wv --
__global__ void k_effw(const float* __restrict__ Wk, const float* __restrict__ Wv,
                       const float* __restrict__ A, const float* __restrict__ M,
                       const float* __restrict__ pri, float* __restrict__ WkA,
                       float* __restrict__ WvM){
  int idx = blockIdx.x*256 + threadIdx.x;
  if (idx >= NTYPE*HID*HID) return;
  int hf = idx & (HID-1);
  int hh = hf >> 4, f = hf & 15;
  int base = idx - hf;
  const float* a  = A + hh*HDIM*HDIM;
  const float* m  = M + hh*HDIM*HDIM;
  const float* wk = Wk + base + hh*HDIM;
  const float* wv = Wv + base + hh*HDIM;
  float sa = 0.f, sm = 0.f;
  #pragma unroll
  for (int d = 0; d < HDIM; ++d){ sa += wk[d]*a[d*HDIM+f]; sm += wv[d]*m[d*HDIM+f]; }
  WkA[idx] = sa * pri[hh] * 0.25f;
  WvM[idx] = sm;
}

// ---- type-bucketed projection GEMM: [64 nodes] x [128] @ W[128][128] x3 ----
// q -> qbuf[N][128]; kA,vm interleaved -> kv[N][256] (kA at +0, vm at +128)
__global__ void __launch_bounds__(256)
k_proj_t(const float* __restrict__ hidden, const float* __restrict__ xnorm,
         const int* __restrict__ tnodes, const int* __restrict__ tcount,
         const int* __restrict__ toffset, const float* __restrict__ Wpos,
         const float* __restrict__ Wq, const float* __restrict__ WkA,
         const float* __restrict__ WvM, float* __restrict__ qout,
         float* __restrict__ kvout){
  int ty   = blockIdx.x / PROJ_BLOCKS_PER_TYPE;
  int tile = blockIdx.x % PROJ_BLOCKS_PER_TYPE;
  int cnt  = tcount[ty];
  int base = tile*TILE_N;
  if (base >= cnt) return;
  __shared__ float hs[TILE_N][HID];
  __shared__ int nl[TILE_N];
  int t  = threadIdx.x;
  int c  = t & 31;          // col tile: cols 4c..4c+3
  int rt = t >> 5;          // node tile: nodes rt*8..rt*8+7
  int off = toffset[ty];
  float4 w0 = *(const float4*)(Wpos + 4*c);
  float4 w1 = *(const float4*)(Wpos + HID + 4*c);
  #pragma unroll
  for (int pass = 0; pass < 8; ++pass){
    int r = pass*8 + rt;
    int node = -1;
    float4 hv = make_float4(0.f,0.f,0.f,0.f);
    if (base + r < cnt){
      node = tnodes[off + base + r];
      float xa0 = xnorm[2*node], xa1 = xnorm[2*node+1];
      float4 hd = *(const float4*)(hidden + (size_t)node*HID + 4*c);
      hv.x = hd.x + xa0*w0.x + xa1*w1.x;
      hv.y = hd.y + xa0*w0.y + xa1*w1.y;
      hv.z = hd.z + xa0*w0.z + xa1*w1.z;
      hv.w = hd.w + xa0*w0.w + xa1*w1.w;
    }
    if (c == 0) nl[r] = node;
    *(float4*)&hs[r][4*c] = hv;
  }
  __syncthreads();

  const float* mats[3] = {Wq + (size_t)ty*HID*HID, WkA + (size_t)ty*HID*HID,
                          WvM + (size_t)ty*HID*HID};
  #pragma unroll 1
  for (int m = 0; m < 3; ++m){
    const float* W = mats[m];
    float4 acc[8];
    #pragma unroll
    for (int r = 0; r < 8; ++r) acc[r] = make_float4(0.f,0.f,0.f,0.f);
    for (int k0 = 0; k0 < HID; k0 += 4){
      float4 hr[8];
      #pragma unroll
      for (int r = 0; r < 8; ++r) hr[r] = *(const float4*)&hs[rt*8+r][k0];
      #pragma unroll
      for (int kk = 0; kk < 4; ++kk){
        float4 w = *(const float4*)(W + (size_t)(k0+kk)*HID + 4*c);
        #pragma unroll
        for (int r = 0; r < 8; ++r){
          float hvv = ((const float*)&hr[r])[kk];
          acc[r].x = fmaf(hvv, w.x, acc[r].x);
          acc[r].y = fmaf(hvv, w.y, acc[r].y);
          acc[r].z = fmaf(hvv, w.z, acc[r].z);
          acc[r].w = fmaf(hvv, w.w, acc[r].w);
        }
      }
    }
    #pragma unroll
    for (int r = 0; r < 8; ++r){
      int node = nl[rt*8+r];
      if (node >= 0){
        if (m == 0)      *(float4*)(qout  + (size_t)node*HID + 4*c)       = acc[r];
        else if (m == 1) *(float4*)(kvout + (size_t)node*2*HID + 4*c)     = acc[r];
        else             *(float4*)(kvout + (size_t)node*2*HID + HID + 4*c) = acc[r];
      }
    }
  }
}

// ---- edge attention: online softmax over CSR, writes trans = gelu(agg) -----
// trans aliases the q buffer (each warp reads q[n] fully before writing).
__global__ void k_edge(const int* __restrict__ rowptr, const int* __restrict__ csr_src,
                       const float* __restrict__ q, const float* __restrict__ kv,
                       float* __restrict__ trans){
  int wid = threadIdx.x >> 6, lane = threadIdx.x & 63;
  int n = blockIdx.x*4 + wid;
  int j = 2*lane;
  int beg = rowptr[n], end = rowptr[n+1];
  float2 qv = *(const float2*)(q + (size_t)n*HID + j);
  float m = -INFINITY, s = 0.f, a0 = 0.f, a1 = 0.f;
  int e = beg;
  for (; e + 2 <= end; e += 2){
    int s0 = csr_src[e], s1 = csr_src[e+1];
    const float* r0 = kv + (size_t)s0*2*HID;
    const float* r1 = kv + (size_t)s1*2*HID;
    float2 k0 = *(const float2*)(r0 + j);
    float2 v0 = *(const float2*)(r0 + HID + j);
    float2 k1 = *(const float2*)(r1 + j);
    float2 v1 = *(const float2*)(r1 + HID + j);
    float p0 = k0.x*qv.x + k0.y*qv.y;
    float p1 = k1.x*qv.x + k1.y*qv.y;
    p0 += __shfl_xor(p0,1); p0 += __shfl_xor(p0,2); p0 += __shfl_xor(p0,4);
    p1 += __shfl_xor(p1,1); p1 += __shfl_xor(p1,2); p1 += __shfl_xor(p1,4);
    float mn  = fmaxf(m, fmaxf(p0, p1));
    float fct = __expf(m - mn);
    float w0  = __expf(p0 - mn), w1 = __expf(p1 - mn);
    s  = s*fct + w0 + w1;
    a0 = a0*fct + w0*v0.x + w1*v1.x;
    a1 = a1*fct + w0*v0.y + w1*v1.y;
    m = mn;
  }
  if (e < end){
    int s0 = csr_src[e];
    const float* r0 = kv + (size_t)s0*2*HID;
    float2 k0 = *(const float2*)(r0 + j);
    float2 v0 = *(const float2*)(r0 + HID + j);
    float p0 = k0.x*qv.x + k0.y*qv.y;
    p0 += __shfl_xor(p0,1); p0 += __shfl_xor(p0,2); p0 += __shfl_xor(p0,4);
    float mn  = fmaxf(m, p0);
    float fct = __expf(m - mn);
    float w0  = __expf(p0 - mn);
    s  = s*fct + w0;
    a0 = a0*fct + w0*v0.x;
    a1 = a1*fct + w0*v0.y;
  }
  float inv = 1.f/(s + 1e-16f);
  *(float2*)(trans + (size_t)n*HID + j) =
      make_float2(gelu_tanh(a0*inv), gelu_tanh(a1*inv));
}

// ---- type-bucketed output GEMM (Wa) + fused epilogue -----------------------
__global__ void __launch_bounds__(256)
k_post_t(const float* __restrict__ trans, const float* __restrict__ xnorm,
         const int* __restrict__ tnodes, const int* __restrict__ tcount,
         const int* __restrict__ toffset, const float* __restrict__ Wpos,
         const float* __restrict__ Wa, const float* __restrict__ skip,
         const float* __restrict__ wpri, float* __restrict__ hidden,
         float* __restrict__ cn, float* __restrict__ pri, int last){
  int ty   = blockIdx.x / PROJ_BLOCKS_PER_TYPE;
  int tile = blockIdx.x % PROJ_BLOCKS_PER_TYPE;
  int cnt  = tcount[ty];
  int base = tile*TILE_N;
  if (base >= cnt) return;
  __shared__ float ts[TILE_N][HID];
  __shared__ int nl[TILE_N];
  int t  = threadIdx.x;
  int c  = t & 31;
  int rt = t >> 5;
  int off = toffset[ty];
  #pragma unroll
  for (int pass = 0; pass < 8; ++pass){
    int r = pass*8 + rt;
    int node = -1;
    float4 tv = make_float4(0.f,0.f,0.f,0.f);
    if (base + r < cnt){
      node = tnodes[off + base + r];
      tv = *(const float4*)(trans + (size_t)node*HID + 4*c);
    }
    if (c == 0) nl[r] = node;
    *(float4*)&ts[r][4*c] = tv;
  }
  __syncthreads();

  const float* W = Wa + (size_t)ty*HID*HID;
  float4 acc[8];
  #pragma unroll
  for (int r = 0; r < 8; ++r) acc[r] = make_float4(0.f,0.f,0.f,0.f);
  for (int k0 = 0; k0 < HID; k0 += 4){
    float4 hr[8];
    #pragma unroll
    for (int r = 0; r < 8; ++r) hr[r] = *(const float4*)&ts[rt*8+r][k0];
    #pragma unroll
    for (int kk = 0; kk < 4; ++kk){
      float4 w = *(const float4*)(W + (size_t)(k0+kk)*HID + 4*c);
      #pragma unroll
      for (int r = 0; r < 8; ++r){
        float hvv = ((const float*)&hr[r])[kk];
        acc[r].x = fmaf(hvv, w.x, acc[r].x);
        acc[r].y = fmaf(hvv, w.y, acc[r].y);
        acc[r].z = fmaf(hvv, w.z, acc[r].z);
        acc[r].w = fmaf(hvv, w.w, acc[r].w);
      }
    }
  }

  float sk = sigmoidf_(skip[ty]);
  float4 w0 = *(const float4*)(Wpos + 4*c);
  float4 w1 = *(const float4*)(Wpos + HID + 4*c);
  float4 wp = *(const float4*)(wpri + 4*c);
  float ppv[8];
  #pragma unroll
  for (int r = 0; r < 8; ++r){
    int node = nl[rt*8+r];
    ppv[r] = 0.f;
    if (node < 0) continue;
    size_t o = (size_t)node*HID + 4*c;
    float xa0 = xnorm[2*node], xa1 = xnorm[2*node+1];
    float4 hd = *(const float4*)(hidden + o);
    float4 cv = *(const float4*)(cn + o);
    float h0 = hd.x + xa0*w0.x + xa1*w1.x;
    float h1 = hd.y + xa0*w0.y + xa1*w1.y;
    float h2 = hd.z + xa0*w0.z + xa1*w1.z;
    float h3 = hd.w + xa0*w0.w + xa1*w1.w;
    float hg0 = sk*acc[r].x + (1.f - sk)*h0;
    float hg1 = sk*acc[r].y + (1.f - sk)*h1;
    float hg2 = sk*acc[r].z + (1.f - sk)*h2;
    float hg3 = sk*acc[r].w + (1.f - sk)*h3;
    ppv[r] = hg0*wp.x + hg1*wp.y + hg2*wp.z + hg3*wp.w;
    float c0 = hg0 + cv.x, c1 = hg1 + cv.y, c2 = hg2 + cv.z, c3 = hg3 + cv.w;
    *(float4*)(cn + o) = make_float4(c0, c1, c2, c3);
    *(float4*)(hidden + o) = make_float4(hd.x + tanhf(c0), hd.y + tanhf(c1),
                                         hd.z + tanhf(c2), hd.w + tanhf(c3));
  }
  if (last){
    #pragma unroll
    for (int r = 0; r < 8; ++r){
      float pp = ppv[r];
      pp += __shfl_xor(pp, 1); pp += __shfl_xor(pp, 2); pp += __shfl_xor(pp, 4);
      pp += __shfl_xor(pp, 8); pp += __shfl_xor(pp, 16);
      ppv[r] = pp;
    }
    if (c == 0){
      #pragma unroll
      for (int r = 0; r < 8; ++r){
        int node = nl[rt*8+r];
        if (node >= 0) pri[node] = sigmoidf_(ppv[r]);
      }
    }
  }
}

// ---- launcher ---------------------------------------------------------------
extern "C" void kernel_launch(void* const* d_in, const int* in_sizes, int n_in,
                              void* d_out, int out_size, void* d_ws, size_t ws_size,
                              hipStream_t stream){
  const float* hidden_in = (const float*)d_in[0];
  const float* cn_in     = (const float*)d_in[1];
  const float* xnorm     = (const float*)d_in[2];
  const int*   ntype     = (const int*)d_in[3];
  const int*   esrc      = (const int*)d_in[4];
  const int*   edst      = (const int*)d_in[5];
  const float* Wpos      = (const float*)d_in[6];
  const float* Wk        = (const float*)d_in[7];
  const float* Wq        = (const float*)d_in[8];
  const float* Wv        = (const float*)d_in[9];
  const float* Wa        = (const float*)d_in[10];
  const float* Ratt      = (const float*)d_in[11];
  const float* Rmsg      = (const float*)d_in[12];
  const float* Rpri      = (const float*)d_in[13];
  const float* Skip      = (const float*)d_in[14];
  const float* Wpri      = (const float*)d_in[15];

  char* ws = (char*)d_ws;
  size_t off = 0;
  auto alloc = [&](size_t bytes)->void*{ void* p = ws + off; off += (bytes + 255) & ~(size_t)255; return p; };
  float* qbuf  = (float*)alloc((size_t)N_NODES*HID*4);     // q, then trans (aliased)
  float* kvbuf = (float*)alloc((size_t)N_NODES*2*HID*4);   // kA | vm interleaved
  float* WkA   = (float*)alloc((size_t)NTYPE*HID*HID*4);
  float* WvM   = (float*)alloc((size_t)NTYPE*HID*HID*4);
  int* deg     = (int*)alloc((size_t)N_NODES*4);
  int* rowptr  = (int*)alloc((size_t)(N_NODES+1)*4);
  int* cursor  = (int*)alloc((size_t)N_NODES*4);
  int* csr     = (int*)alloc((size_t)N_EDGES*4);
  int* tcount  = (int*)alloc(8*4);
  int* toffset = (int*)alloc(8*4);
  int* tcursor = (int*)alloc(8*4);
  int* tnodes  = (int*)alloc((size_t)N_NODES*4);

  float* out_hidden = (float*)d_out;
  float* out_cn     = out_hidden + (size_t)N_NODES*HID;
  float* out_pri    = out_cn     + (size_t)N_NODES*HID;

  hipMemsetAsync(deg,     0, (size_t)N_NODES*4, stream);
  hipMemsetAsync(cursor,  0, (size_t)N_NODES*4, stream);
  hipMemsetAsync(tcount,  0, 8*4, stream);
  hipMemsetAsync(tcursor, 0, 8*4, stream);
  k_hist<<<(N_EDGES+255)/256, 256, 0, stream>>>(edst, deg);
  k_scan<<<1, 256, 0, stream>>>(deg, rowptr);
  k_fill<<<(N_EDGES+255)/256, 256, 0, stream>>>(esrc, edst, rowptr, cursor, csr);
  k_thist<<<(N_NODES+255)/256, 256, 0, stream>>>(ntype, tcount);
  k_tscan<<<1, 64, 0, stream>>>(tcount, toffset);
  k_tfill<<<(N_NODES+255)/256, 256, 0, stream>>>(ntype, toffset, tcursor, tnodes);

  hipMemcpyAsync(out_hidden, hidden_in, (size_t)N_NODES*HID*4, hipMemcpyDeviceToDevice, stream);
  hipMemcpyAsync(out_cn,     cn_in,     (size_t)N_NODES*HID*4, hipMemcpyDeviceToDevice, stream);

  const int proj_grid = NTYPE * PROJ_BLOCKS_PER_TYPE;
  for (int l = 0; l < NLAYER; ++l){
    const float* Wpos_l = Wpos + (size_t)l*2*HID;
    const float* Wk_l   = Wk   + (size_t)l*NTYPE*HID*HID;
    const float* Wq_l   = Wq   + (size_t)l*NTYPE*HID*HID;
    const float* Wv_l   = Wv   + (size_t)l*NTYPE*HID*HID;
    const float* Wa_l   = Wa   + (size_t)l*NTYPE*HID*HID;
    const float* Ratt_l = Ratt + (size_t)l*NHEAD*HDIM*HDIM;
    const float* Rmsg_l = Rmsg + (size_t)l*NHEAD*HDIM*HDIM;
    const float* Rpri_l = Rpri + (size_t)l*NHEAD;
    const float* Skip_l = Skip + (size_t)l*NTYPE;
    const float* Wpri_l = Wpri + (size_t)l*HID;

    k_effw<<<(NTYPE*HID*HID+255)/256, 256, 0, stream>>>(Wk_l, Wv_l, Ratt_l, Rmsg_l, Rpri_l, WkA, WvM);
    k_proj_t<<<proj_grid, 256, 0, stream>>>(out_hidden, xnorm, tnodes, tcount, toffset,
                                            Wpos_l, Wq_l, WkA, WvM, qbuf, kvbuf);
    k_edge<<<N_NODES/4, 256, 0, stream>>>(rowptr, csr, qbuf, kvbuf, qbuf);
    k_post_t<<<proj_grid, 256, 0, stream>>>(qbuf, xnorm, tnodes, tcount, toffset,
                                            Wpos_l, Wa_l, Skip_l, Wpri_l,
                                            out_hidden, out_cn, out_pri, l == NLAYER-1);
  }
}

// Round 7
// 687.334 us; speedup vs baseline: 2.8422x; 1.2191x over previous
//
#include <hip/hip_runtime.h>
#include <hip/hip_bf16.h>
#include <math.h>

#define N_NODES 50000
#define N_EDGES 800000
#define HID     128
#define NHEAD   8
#define HDIM    16
#define NTYPE   6
#define NLAYER  2
#define TILE_N  64
#define PROJ_BLOCKS_PER_TYPE 782   // ceil(50000/64) worst case, one type owns all nodes

typedef unsigned int uint_;
typedef unsigned short ushort_;

__device__ __forceinline__ float sigmoidf_(float x){ return 1.f/(1.f+__expf(-x)); }
__device__ __forceinline__ float gelu_tanh(float x){
  float x3 = x*x*x;
  return 0.5f*x*(1.f + tanhf(0.7978845608028654f*(x + 0.044715f*x3)));
}
// fp32 -> bf16 (RNE), packed pair
__device__ __forceinline__ uint_ pack_bf2(float lo, float hi){
  union{float f; uint_ u;} a, b; a.f = lo; b.f = hi;
  uint_ ua = (a.u + 0x7FFFu + ((a.u >> 16) & 1u)) >> 16;
  uint_ ub = (b.u + 0x7FFFu + ((b.u >> 16) & 1u)) & 0xFFFF0000u;
  return ua | ub;
}

// ---- CSR build --------------------------------------------------------------
__global__ void k_hist(const int* __restrict__ edst, int* __restrict__ deg){
  int e = blockIdx.x*256 + threadIdx.x;
  if (e < N_EDGES) atomicAdd(&deg[edst[e]], 1);
}

__global__ void k_scan(const int* __restrict__ deg, int* __restrict__ rowptr){
  __shared__ int part[256];
  const int chunk = (N_NODES + 255)/256;
  int t = threadIdx.x;
  int beg = t*chunk, end = min(beg+chunk, N_NODES);
  int s = 0;
  for (int i = beg; i < end; ++i) s += deg[i];
  part[t] = s;
  __syncthreads();
  if (t == 0){
    int acc = 0;
    for (int i = 0; i < 256; ++i){ int v = part[i]; part[i] = acc; acc += v; }
    rowptr[N_NODES] = acc;
  }
  __syncthreads();
  int acc = part[t];
  for (int i = beg; i < end; ++i){ rowptr[i] = acc; acc += deg[i]; }
}

__global__ void k_fill(const int* __restrict__ esrc, const int* __restrict__ edst,
                       const int* __restrict__ rowptr, int* __restrict__ cursor,
                       int* __restrict__ csr_src){
  int e = blockIdx.x*256 + threadIdx.x;
  if (e < N_EDGES){
    int d = edst[e];
    int pos = atomicAdd(&cursor[d], 1);
    csr_src[rowptr[d] + pos] = esrc[e];
  }
}

// ---- type bucketing (block-aggregated: ~6 global atomics per block) --------
__global__ void k_thist(const int* __restrict__ ntype, int* __restrict__ tcount){
  __shared__ int c[NTYPE];
  int t = threadIdx.x;
  if (t < NTYPE) c[t] = 0;
  __syncthreads();
  int n = blockIdx.x*256 + t;
  if (n < N_NODES) atomicAdd(&c[ntype[n]], 1);
  __syncthreads();
  if (t < NTYPE && c[t] > 0) atomicAdd(&tcount[t], c[t]);
}

__global__ void k_tscan(const int* __restrict__ tcount, int* __restrict__ toffset){
  if (threadIdx.x == 0){
    int acc = 0;
    for (int i = 0; i < NTYPE; ++i){ toffset[i] = acc; acc += tcount[i]; }
  }
}

__global__ void k_tfill(const int* __restrict__ ntype, const int* __restrict__ toffset,
                        int* __restrict__ tcursor, int* __restrict__ tnodes){
  __shared__ int c[NTYPE], base[NTYPE];
  int t = threadIdx.x;
  if (t < NTYPE) c[t] = 0;
  __syncthreads();
  int n = blockIdx.x*256 + t;
  int ty = 0, rank = 0;
  bool valid = (n < N_NODES);
  if (valid){ ty = ntype[n]; rank = atomicAdd(&c[ty], 1); }
  __syncthreads();
  if (t < NTYPE && c[t] > 0) base[t] = atomicAdd(&tcursor[t], c[t]);
  __syncthreads();
  if (valid) tnodes[toffset[ty] + base[ty] + rank] = n;
}

// ---- effective weights: fold rel_att/rel_msg (+rel_pri/sqrt(D)) into Wk/Wv --
__global__ void k_effw(const float* __restrict__ Wk, const float* __restrict__ Wv,
                       const float* __restrict__ A, const float* __restrict__ M,
                       const float* __restrict__ pri, float* __restrict__ WkA,
                       float* __restrict__ WvM){
  int idx = blockIdx.x*256 + threadIdx.x;
  if (idx >= NTYPE*HID*HID) return;
  int hf = idx & (HID-1);
  int hh = hf >> 4, f = hf & 15;
  int base = idx - hf;
  const float* a  = A + hh*HDIM*HDIM;
  const float* m  = M + hh*HDIM*HDIM;
  const float* wk = Wk + base + hh*HDIM;
  const float* wv = Wv + base + hh*HDIM;
  float sa = 0.f, sm = 0.f;
  #pragma unroll
  for (int d = 0; d < HDIM; ++d){ sa += wk[d]*a[d*HDIM+f]; sm += wv[d]*m[d*HDIM+f]; }
  WkA[idx] = sa * pri[hh] * 0.25f;
  WvM[idx] = sm;
}

// ---- type-bucketed projection GEMM: q fp32; kA|vm packed bf16 -> kv[N][256]
__global__ void __launch_bounds__(256)
k_proj_t(const float* __restrict__ hidden, const float* __restrict__ xnorm,
         const int* __restrict__ tnodes, const int* __restrict__ tcount,
         const int* __restrict__ toffset, const float* __restrict__ Wpos,
         const float* __restrict__ Wq, const float* __restrict__ WkA,
         const float* __restrict__ WvM, float* __restrict__ qout,
         ushort_* __restrict__ kvout){
  int ty   = blockIdx.x / PROJ_BLOCKS_PER_TYPE;
  int tile = blockIdx.x % PROJ_BLOCKS_PER_TYPE;
  int cnt  = tcount[ty];
  int base = tile*TILE_N;
  if (base >= cnt) return;
  __shared__ float hs[TILE_N][HID];
  __shared__ int nl[TILE_N];
  int t  = threadIdx.x;
  int c  = t & 31;          // col tile: cols 4c..4c+3
  int rt = t >> 5;          // node tile: nodes rt*8..rt*8+7
  int off = toffset[ty];
  float4 w0 = *(const float4*)(Wpos + 4*c);
  float4 w1 = *(const float4*)(Wpos + HID + 4*c);
  #pragma unroll
  for (int pass = 0; pass < 8; ++pass){
    int r = pass*8 + rt;
    int node = -1;
    float4 hv = make_float4(0.f,0.f,0.f,0.f);
    if (base + r < cnt){
      node = tnodes[off + base + r];
      float xa0 = xnorm[2*node], xa1 = xnorm[2*node+1];
      float4 hd = *(const float4*)(hidden + (size_t)node*HID + 4*c);
      hv.x = hd.x + xa0*w0.x + xa1*w1.x;
      hv.y = hd.y + xa0*w0.y + xa1*w1.y;
      hv.z = hd.z + xa0*w0.z + xa1*w1.z;
      hv.w = hd.w + xa0*w0.w + xa1*w1.w;
    }
    if (c == 0) nl[r] = node;
    *(float4*)&hs[r][4*c] = hv;
  }
  __syncthreads();

  const float* mats[3] = {Wq + (size_t)ty*HID*HID, WkA + (size_t)ty*HID*HID,
                          WvM + (size_t)ty*HID*HID};
  #pragma unroll 1
  for (int m = 0; m < 3; ++m){
    const float* W = mats[m];
    float4 acc[8];
    #pragma unroll
    for (int r = 0; r < 8; ++r) acc[r] = make_float4(0.f,0.f,0.f,0.f);
    for (int k0 = 0; k0 < HID; k0 += 4){
      float4 hr[8];
      #pragma unroll
      for (int r = 0; r < 8; ++r) hr[r] = *(const float4*)&hs[rt*8+r][k0];
      #pragma unroll
      for (int kk = 0; kk < 4; ++kk){
        float4 w = *(const float4*)(W + (size_t)(k0+kk)*HID + 4*c);
        #pragma unroll
        for (int r = 0; r < 8; ++r){
          float hvv = ((const float*)&hr[r])[kk];
          acc[r].x = fmaf(hvv, w.x, acc[r].x);
          acc[r].y = fmaf(hvv, w.y, acc[r].y);
          acc[r].z = fmaf(hvv, w.z, acc[r].z);
          acc[r].w = fmaf(hvv, w.w, acc[r].w);
        }
      }
    }
    #pragma unroll
    for (int r = 0; r < 8; ++r){
      int node = nl[rt*8+r];
      if (node >= 0){
        if (m == 0){
          *(float4*)(qout + (size_t)node*HID + 4*c) = acc[r];
        } else {
          uint2 pk = make_uint2(pack_bf2(acc[r].x, acc[r].y),
                                pack_bf2(acc[r].z, acc[r].w));
          size_t o = (size_t)node*2*HID + (m == 2 ? HID : 0) + 4*c;
          *(uint2*)(kvout + o) = pk;
        }
      }
    }
  }
}

// ---- edge attention: bf16 kv gather, online softmax, writes trans ----------
__global__ void k_edge(const int* __restrict__ rowptr, const int* __restrict__ csr_src,
                       const float* __restrict__ q, const ushort_* __restrict__ kv,
                       float* __restrict__ trans){
  int wid = threadIdx.x >> 6, lane = threadIdx.x & 63;
  int n = blockIdx.x*4 + wid;
  int j = 2*lane;
  int beg = rowptr[n], end = rowptr[n+1];
  float2 qv = *(const float2*)(q + (size_t)n*HID + j);
  float m = -INFINITY, s = 0.f, a0 = 0.f, a1 = 0.f;
  int e = beg;
  for (; e + 4 <= end; e += 4){
    uint_ kb[4], vb[4];
    float p[4];
    #pragma unroll
    for (int u = 0; u < 4; ++u){
      const ushort_* r0 = kv + (size_t)csr_src[e+u]*2*HID + j;
      kb[u] = *(const uint_*)r0;
      vb[u] = *(const uint_*)(r0 + HID);
    }
    #pragma unroll
    for (int u = 0; u < 4; ++u){
      float kx = __uint_as_float(kb[u] << 16);
      float ky = __uint_as_float(kb[u] & 0xFFFF0000u);
      float pp = kx*qv.x + ky*qv.y;
      pp += __shfl_xor(pp,1); pp += __shfl_xor(pp,2); pp += __shfl_xor(pp,4);
      p[u] = pp;
    }
    float mn = fmaxf(fmaxf(p[0],p[1]), fmaxf(p[2],p[3]));
    mn = fmaxf(m, mn);
    float fct = __expf(m - mn);
    s *= fct; a0 *= fct; a1 *= fct;
    #pragma unroll
    for (int u = 0; u < 4; ++u){
      float w = __expf(p[u] - mn);
      float vx = __uint_as_float(vb[u] << 16);
      float vy = __uint_as_float(vb[u] & 0xFFFF0000u);
      s += w; a0 = fmaf(w, vx, a0); a1 = fmaf(w, vy, a1);
    }
    m = mn;
  }
  for (; e < end; ++e){
    const ushort_* r0 = kv + (size_t)csr_src[e]*2*HID + j;
    uint_ kb = *(const uint_*)r0;
    uint_ vb = *(const uint_*)(r0 + HID);
    float kx = __uint_as_float(kb << 16);
    float ky = __uint_as_float(kb & 0xFFFF0000u);
    float pp = kx*qv.x + ky*qv.y;
    pp += __shfl_xor(pp,1); pp += __shfl_xor(pp,2); pp += __shfl_xor(pp,4);
    float mn  = fmaxf(m, pp);
    float fct = __expf(m - mn);
    float w   = __expf(pp - mn);
    float vx = __uint_as_float(vb << 16);
    float vy = __uint_as_float(vb & 0xFFFF0000u);
    s  = s*fct + w;
    a0 = fmaf(w, vx, a0*fct);
    a1 = fmaf(w, vy, a1*fct);
    m = mn;
  }
  float inv = 1.f/(s + 1e-16f);
  *(float2*)(trans + (size_t)n*HID + j) =
      make_float2(gelu_tanh(a0*inv), gelu_tanh(a1*inv));
}

// ---- type-bucketed output GEMM (Wa) + fused epilogue -----------------------
__global__ void __launch_bounds__(256)
k_post_t(const float* __restrict__ trans, const float* __restrict__ xnorm,
         const int* __restrict__ tnodes, const int* __restrict__ tcount,
         const int* __restrict__ toffset, const float* __restrict__ Wpos,
         const float* __restrict__ Wa, const float* __restrict__ skip,
         const float* __restrict__ wpri,
         const float* __restrict__ hsrc, const float* __restrict__ csrc,
         float* __restrict__ hdst, float* __restrict__ cdst,
         float* __restrict__ pri, int last){
  int ty   = blockIdx.x / PROJ_BLOCKS_PER_TYPE;
  int tile = blockIdx.x % PROJ_BLOCKS_PER_TYPE;
  int cnt  = tcount[ty];
  int base = tile*TILE_N;
  if (base >= cnt) return;
  __shared__ float ts[TILE_N][HID];
  __shared__ int nl[TILE_N];
  int t  = threadIdx.x;
  int c  = t & 31;
  int rt = t >> 5;
  int off = toffset[ty];
  #pragma unroll
  for (int pass = 0; pass < 8; ++pass){
    int r = pass*8 + rt;
    int node = -1;
    float4 tv = make_float4(0.f,0.f,0.f,0.f);
    if (base + r < cnt){
      node = tnodes[off + base + r];
      tv = *(const float4*)(trans + (size_t)node*HID + 4*c);
    }
    if (c == 0) nl[r] = node;
    *(float4*)&ts[r][4*c] = tv;
  }
  __syncthreads();

  const float* W = Wa + (size_t)ty*HID*HID;
  float4 acc[8];
  #pragma unroll
  for (int r = 0; r < 8; ++r) acc[r] = make_float4(0.f,0.f,0.f,0.f);
  for (int k0 = 0; k0 < HID; k0 += 4){
    float4 hr[8];
    #pragma unroll
    for (int r = 0; r < 8; ++r) hr[r] = *(const float4*)&ts[rt*8+r][k0];
    #pragma unroll
    for (int kk = 0; kk < 4; ++kk){
      float4 w = *(const float4*)(W + (size_t)(k0+kk)*HID + 4*c);
      #pragma unroll
      for (int r = 0; r < 8; ++r){
        float hvv = ((const float*)&hr[r])[kk];
        acc[r].x = fmaf(hvv, w.x, acc[r].x);
        acc[r].y = fmaf(hvv, w.y, acc[r].y);
        acc[r].z = fmaf(hvv, w.z, acc[r].z);
        acc[r].w = fmaf(hvv, w.w, acc[r].w);
      }
    }
  }

  float sk = sigmoidf_(skip[ty]);
  float4 w0 = *(const float4*)(Wpos + 4*c);
  float4 w1 = *(const float4*)(Wpos + HID + 4*c);
  float4 wp = *(const float4*)(wpri + 4*c);
  float ppv[8];
  #pragma unroll
  for (int r = 0; r < 8; ++r){
    int node = nl[rt*8+r];
    ppv[r] = 0.f;
    if (node < 0) continue;
    size_t o = (size_t)node*HID + 4*c;
    float xa0 = xnorm[2*node], xa1 = xnorm[2*node+1];
    float4 hd = *(const float4*)(hsrc + o);
    float4 cv = *(const float4*)(csrc + o);
    float h0 = hd.x + xa0*w0.x + xa1*w1.x;
    float h1 = hd.y + xa0*w0.y + xa1*w1.y;
    float h2 = hd.z + xa0*w0.z + xa1*w1.z;
    float h3 = hd.w + xa0*w0.w + xa1*w1.w;
    float hg0 = sk*acc[r].x + (1.f - sk)*h0;
    float hg1 = sk*acc[r].y + (1.f - sk)*h1;
    float hg2 = sk*acc[r].z + (1.f - sk)*h2;
    float hg3 = sk*acc[r].w + (1.f - sk)*h3;
    ppv[r] = hg0*wp.x + hg1*wp.y + hg2*wp.z + hg3*wp.w;
    float c0 = hg0 + cv.x, c1 = hg1 + cv.y, c2 = hg2 + cv.z, c3 = hg3 + cv.w;
    *(float4*)(cdst + o) = make_float4(c0, c1, c2, c3);
    *(float4*)(hdst + o) = make_float4(hd.x + tanhf(c0), hd.y + tanhf(c1),
                                       hd.z + tanhf(c2), hd.w + tanhf(c3));
  }
  if (last){
    #pragma unroll
    for (int r = 0; r < 8; ++r){
      float pp = ppv[r];
      pp += __shfl_xor(pp, 1); pp += __shfl_xor(pp, 2); pp += __shfl_xor(pp, 4);
      pp += __shfl_xor(pp, 8); pp += __shfl_xor(pp, 16);
      ppv[r] = pp;
    }
    if (c == 0){
      #pragma unroll
      for (int r = 0; r < 8; ++r){
        int node = nl[rt*8+r];
        if (node >= 0) pri[node] = sigmoidf_(ppv[r]);
      }
    }
  }
}

// ---- launcher ---------------------------------------------------------------
extern "C" void kernel_launch(void* const* d_in, const int* in_sizes, int n_in,
                              void* d_out, int out_size, void* d_ws, size_t ws_size,
                              hipStream_t stream){
  const float* hidden_in = (const float*)d_in[0];
  const float* cn_in     = (const float*)d_in[1];
  const float* xnorm     = (const float*)d_in[2];
  const int*   ntype     = (const int*)d_in[3];
  const int*   esrc      = (const int*)d_in[4];
  const int*   edst      = (const int*)d_in[5];
  const float* Wpos      = (const float*)d_in[6];
  const float* Wk        = (const float*)d_in[7];
  const float* Wq        = (const float*)d_in[8];
  const float* Wv        = (const float*)d_in[9];
  const float* Wa        = (const float*)d_in[10];
  const float* Ratt      = (const float*)d_in[11];
  const float* Rmsg      = (const float*)d_in[12];
  const float* Rpri      = (const float*)d_in[13];
  const float* Skip      = (const float*)d_in[14];
  const float* Wpri      = (const float*)d_in[15];

  char* ws = (char*)d_ws;
  size_t off = 0;
  auto alloc = [&](size_t bytes)->void*{ void* p = ws + off; off += (bytes + 255) & ~(size_t)255; return p; };
  float*   qbuf  = (float*)alloc((size_t)N_NODES*HID*4);      // q, then trans (aliased)
  ushort_* kvbuf = (ushort_*)alloc((size_t)N_NODES*2*HID*2);  // bf16 kA | vm
  float* WkA   = (float*)alloc((size_t)NTYPE*HID*HID*4);
  float* WvM   = (float*)alloc((size_t)NTYPE*HID*HID*4);
  int* deg     = (int*)alloc((size_t)N_NODES*4);
  int* rowptr  = (int*)alloc((size_t)(N_NODES+1)*4);
  int* cursor  = (int*)alloc((size_t)N_NODES*4);
  int* csr     = (int*)alloc((size_t)N_EDGES*4);
  int* tcount  = (int*)alloc(8*4);
  int* toffset = (int*)alloc(8*4);
  int* tcursor = (int*)alloc(8*4);
  int* tnodes  = (int*)alloc((size_t)N_NODES*4);

  float* out_hidden = (float*)d_out;
  float* out_cn     = out_hidden + (size_t)N_NODES*HID;
  float* out_pri    = out_cn     + (size_t)N_NODES*HID;

  hipMemsetAsync(deg,     0, (size_t)N_NODES*4, stream);
  hipMemsetAsync(cursor,  0, (size_t)N_NODES*4, stream);
  hipMemsetAsync(tcount,  0, 8*4, stream);
  hipMemsetAsync(tcursor, 0, 8*4, stream);
  k_hist<<<(N_EDGES+255)/256, 256, 0, stream>>>(edst, deg);
  k_scan<<<1, 256, 0, stream>>>(deg, rowptr);
  k_fill<<<(N_EDGES+255)/256, 256, 0, stream>>>(esrc, edst, rowptr, cursor, csr);
  k_thist<<<(N_NODES+255)/256, 256, 0, stream>>>(ntype, tcount);
  k_tscan<<<1, 64, 0, stream>>>(tcount, toffset);
  k_tfill<<<(N_NODES+255)/256, 256, 0, stream>>>(ntype, toffset, tcursor, tnodes);

  const int proj_grid = NTYPE * PROJ_BLOCKS_PER_TYPE;
  for (int l = 0; l < NLAYER; ++l){
    const float* Wpos_l = Wpos + (size_t)l*2*HID;
    const float* Wq_l   = Wq   + (size_t)l*NTYPE*HID*HID;
    const float* Wk_l   = Wk   + (size_t)l*NTYPE*HID*HID;
    const float* Wv_l   = Wv   + (size_t)l*NTYPE*HID*HID;
    const float* Wa_l   = Wa   + (size_t)l*NTYPE*HID*HID;
    const float* Ratt_l = Ratt + (size_t)l*NHEAD*HDIM*HDIM;
    const float* Rmsg_l = Rmsg + (size_t)l*NHEAD*HDIM*HDIM;
    const float* Rpri_l = Rpri + (size_t)l*NHEAD;
    const float* Skip_l = Skip + (size_t)l*NTYPE;
    const float* Wpri_l = Wpri + (size_t)l*HID;

    const float* hsrc = (l == 0) ? hidden_in : out_hidden;
    const float* csrc = (l == 0) ? cn_in     : out_cn;

    k_effw<<<(NTYPE*HID*HID+255)/256, 256, 0, stream>>>(Wk_l, Wv_l, Ratt_l, Rmsg_l, Rpri_l, WkA, WvM);
    k_proj_t<<<proj_grid, 256, 0, stream>>>(hsrc, xnorm, tnodes, tcount, toffset,
                                            Wpos_l, Wq_l, WkA, WvM, qbuf, kvbuf);
    k_edge<<<N_NODES/4, 256, 0, stream>>>(rowptr, csr, qbuf, kvbuf, qbuf);
    k_post_t<<<proj_grid, 256, 0, stream>>>(qbuf, xnorm, tnodes, tcount, toffset,
                                            Wpos_l, Wa_l, Skip_l, Wpri_l,
                                            hsrc, csrc, out_hidden, out_cn,
                                            out_pri, l == NLAYER-1);
  }
}

// Round 8
// 675.851 us; speedup vs baseline: 2.8905x; 1.0170x over previous
//
#include <hip/hip_runtime.h>
#include <hip/hip_bf16.h>
#include <math.h>

#define N_NODES 50000
#define N_EDGES 800000
#define HID     128
#define NHEAD   8
#define HDIM    16
#define NTYPE   6
#define NLAYER  2
#define TILE_N  64
#define PROJ_BLOCKS_PER_TYPE 782   // ceil(50000/64) worst case, one type owns all nodes

typedef unsigned int uint_;
typedef unsigned short ushort_;

__device__ __forceinline__ float sigmoidf_(float x){ return 1.f/(1.f+__expf(-x)); }
__device__ __forceinline__ float gelu_tanh(float x){
  float x3 = x*x*x;
  return 0.5f*x*(1.f + tanhf(0.7978845608028654f*(x + 0.044715f*x3)));
}
// fp32 -> bf16 (RNE), packed pair
__device__ __forceinline__ uint_ pack_bf2(float lo, float hi){
  union{float f; uint_ u;} a, b; a.f = lo; b.f = hi;
  uint_ ua = (a.u + 0x7FFFu + ((a.u >> 16) & 1u)) >> 16;
  uint_ ub = (b.u + 0x7FFFu + ((b.u >> 16) & 1u)) & 0xFFFF0000u;
  return ua | ub;
}

// ---- CSR build --------------------------------------------------------------
__global__ void k_hist(const int* __restrict__ edst, int* __restrict__ deg){
  int e = blockIdx.x*256 + threadIdx.x;
  if (e < N_EDGES) atomicAdd(&deg[edst[e]], 1);
}

__global__ void __launch_bounds__(1024)
k_scan(const int* __restrict__ deg, int* __restrict__ rowptr){
  __shared__ int part[1024];
  const int chunk = (N_NODES + 1023)/1024;   // 49
  int t = threadIdx.x;
  int beg = t*chunk, end = min(beg+chunk, N_NODES);
  int s = 0;
  for (int i = beg; i < end; ++i) s += deg[i];
  part[t] = s;
  __syncthreads();
  if (t == 0){
    int acc = 0;
    for (int i = 0; i < 1024; ++i){ int v = part[i]; part[i] = acc; acc += v; }
    rowptr[N_NODES] = acc;
  }
  __syncthreads();
  int acc = part[t];
  for (int i = beg; i < end; ++i){ rowptr[i] = acc; acc += deg[i]; }
}

__global__ void k_fill(const int* __restrict__ esrc, const int* __restrict__ edst,
                       const int* __restrict__ rowptr, int* __restrict__ cursor,
                       int* __restrict__ csr_src){
  int e = blockIdx.x*256 + threadIdx.x;
  if (e < N_EDGES){
    int d = edst[e];
    int pos = atomicAdd(&cursor[d], 1);
    csr_src[rowptr[d] + pos] = esrc[e];
  }
}

// ---- type bucketing (block-aggregated: ~6 global atomics per block) --------
__global__ void k_thist(const int* __restrict__ ntype, int* __restrict__ tcount){
  __shared__ int c[NTYPE];
  int t = threadIdx.x;
  if (t < NTYPE) c[t] = 0;
  __syncthreads();
  int n = blockIdx.x*256 + t;
  if (n < N_NODES) atomicAdd(&c[ntype[n]], 1);
  __syncthreads();
  if (t < NTYPE && c[t] > 0) atomicAdd(&tcount[t], c[t]);
}

__global__ void k_tscan(const int* __restrict__ tcount, int* __restrict__ toffset){
  if (threadIdx.x == 0){
    int acc = 0;
    for (int i = 0; i < NTYPE; ++i){ toffset[i] = acc; acc += tcount[i]; }
  }
}

__global__ void k_tfill(const int* __restrict__ ntype, const int* __restrict__ toffset,
                        int* __restrict__ tcursor, int* __restrict__ tnodes){
  __shared__ int c[NTYPE], base[NTYPE];
  int t = threadIdx.x;
  if (t < NTYPE) c[t] = 0;
  __syncthreads();
  int n = blockIdx.x*256 + t;
  int ty = 0, rank = 0;
  bool valid = (n < N_NODES);
  if (valid){ ty = ntype[n]; rank = atomicAdd(&c[ty], 1); }
  __syncthreads();
  if (t < NTYPE && c[t] > 0) base[t] = atomicAdd(&tcursor[t], c[t]);
  __syncthreads();
  if (valid) tnodes[toffset[ty] + base[ty] + rank] = n;
}

// ---- effective weights: fold rel_att/rel_msg (+rel_pri/sqrt(D)) into Wk/Wv --
__global__ void k_effw(const float* __restrict__ Wk, const float* __restrict__ Wv,
                       const float* __restrict__ A, const float* __restrict__ M,
                       const float* __restrict__ pri, float* __restrict__ WkA,
                       float* __restrict__ WvM){
  int idx = blockIdx.x*256 + threadIdx.x;
  if (idx >= NTYPE*HID*HID) return;
  int hf = idx & (HID-1);
  int hh = hf >> 4, f = hf & 15;
  int base = idx - hf;
  const float* a  = A + hh*HDIM*HDIM;
  const float* m  = M + hh*HDIM*HDIM;
  const float* wk = Wk + base + hh*HDIM;
  const float* wv = Wv + base + hh*HDIM;
  float sa = 0.f, sm = 0.f;
  #pragma unroll
  for (int d = 0; d < HDIM; ++d){ sa += wk[d]*a[d*HDIM+f]; sm += wv[d]*m[d*HDIM+f]; }
  WkA[idx] = sa * pri[hh] * 0.25f;
  WvM[idx] = sm;
}

// ---- type-bucketed projection GEMM, one matrix per block -------------------
// blockIdx.x = (ty*PBT + tile)*3 + m;  m: 0=Wq->qout(fp32), 1=WkA, 2=WvM (bf16 kv)
__global__ void __launch_bounds__(256)
k_proj_t(const float* __restrict__ hidden, const float* __restrict__ xnorm,
         const int* __restrict__ tnodes, const int* __restrict__ tcount,
         const int* __restrict__ toffset, const float* __restrict__ Wpos,
         const float* __restrict__ Wq, const float* __restrict__ WkA,
         const float* __restrict__ WvM, float* __restrict__ qout,
         ushort_* __restrict__ kvout){
  int bid  = blockIdx.x;
  int m    = bid % 3;
  int rest = bid / 3;
  int ty   = rest / PROJ_BLOCKS_PER_TYPE;
  int tile = rest % PROJ_BLOCKS_PER_TYPE;
  int cnt  = tcount[ty];
  int base = tile*TILE_N;
  if (base >= cnt) return;
  __shared__ float hs[TILE_N][HID];
  __shared__ int nl[TILE_N];
  int t  = threadIdx.x;
  int c  = t & 31;          // col tile: cols 4c..4c+3
  int rt = t >> 5;          // node tile: nodes rt..56+rt step 8
  int off = toffset[ty];
  float4 w0 = *(const float4*)(Wpos + 4*c);
  float4 w1 = *(const float4*)(Wpos + HID + 4*c);
  #pragma unroll
  for (int pass = 0; pass < 8; ++pass){
    int r = pass*8 + rt;
    int node = -1;
    float4 hv = make_float4(0.f,0.f,0.f,0.f);
    if (base + r < cnt){
      node = tnodes[off + base + r];
      float xa0 = xnorm[2*node], xa1 = xnorm[2*node+1];
      float4 hd = *(const float4*)(hidden + (size_t)node*HID + 4*c);
      hv.x = hd.x + xa0*w0.x + xa1*w1.x;
      hv.y = hd.y + xa0*w0.y + xa1*w1.y;
      hv.z = hd.z + xa0*w0.z + xa1*w1.z;
      hv.w = hd.w + xa0*w0.w + xa1*w1.w;
    }
    if (c == 0) nl[r] = node;
    *(float4*)&hs[r][4*c] = hv;
  }
  __syncthreads();

  const float* W = (m == 0 ? Wq : (m == 1 ? WkA : WvM)) + (size_t)ty*HID*HID;
  float4 acc[8];
  #pragma unroll
  for (int r = 0; r < 8; ++r) acc[r] = make_float4(0.f,0.f,0.f,0.f);
  for (int k0 = 0; k0 < HID; k0 += 4){
    float4 hr[8];
    #pragma unroll
    for (int r = 0; r < 8; ++r) hr[r] = *(const float4*)&hs[rt*8+r][k0];
    #pragma unroll
    for (int kk = 0; kk < 4; ++kk){
      float4 w = *(const float4*)(W + (size_t)(k0+kk)*HID + 4*c);
      #pragma unroll
      for (int r = 0; r < 8; ++r){
        float hvv = ((const float*)&hr[r])[kk];
        acc[r].x = fmaf(hvv, w.x, acc[r].x);
        acc[r].y = fmaf(hvv, w.y, acc[r].y);
        acc[r].z = fmaf(hvv, w.z, acc[r].z);
        acc[r].w = fmaf(hvv, w.w, acc[r].w);
      }
    }
  }
  #pragma unroll
  for (int r = 0; r < 8; ++r){
    int node = nl[rt*8+r];
    if (node >= 0){
      if (m == 0){
        *(float4*)(qout + (size_t)node*HID + 4*c) = acc[r];
      } else {
        uint2 pk = make_uint2(pack_bf2(acc[r].x, acc[r].y),
                              pack_bf2(acc[r].z, acc[r].w));
        size_t o = (size_t)node*2*HID + (m == 2 ? HID : 0) + 4*c;
        *(uint2*)(kvout + o) = pk;
      }
    }
  }
}

// ---- edge attention: bf16 kv gather, online softmax, writes trans ----------
__global__ void k_edge(const int* __restrict__ rowptr, const int* __restrict__ csr_src,
                       const float* __restrict__ q, const ushort_* __restrict__ kv,
                       float* __restrict__ trans){
  int wid = threadIdx.x >> 6, lane = threadIdx.x & 63;
  int n = blockIdx.x*4 + wid;
  int j = 2*lane;
  int beg = rowptr[n], end = rowptr[n+1];
  float2 qv = *(const float2*)(q + (size_t)n*HID + j);
  float m = -INFINITY, s = 0.f, a0 = 0.f, a1 = 0.f;
  int e = beg;
  for (; e + 4 <= end; e += 4){
    uint_ kb[4], vb[4];
    float p[4];
    #pragma unroll
    for (int u = 0; u < 4; ++u){
      const ushort_* r0 = kv + (size_t)csr_src[e+u]*2*HID + j;
      kb[u] = *(const uint_*)r0;
      vb[u] = *(const uint_*)(r0 + HID);
    }
    #pragma unroll
    for (int u = 0; u < 4; ++u){
      float kx = __uint_as_float(kb[u] << 16);
      float ky = __uint_as_float(kb[u] & 0xFFFF0000u);
      float pp = kx*qv.x + ky*qv.y;
      pp += __shfl_xor(pp,1); pp += __shfl_xor(pp,2); pp += __shfl_xor(pp,4);
      p[u] = pp;
    }
    float mn = fmaxf(fmaxf(p[0],p[1]), fmaxf(p[2],p[3]));
    mn = fmaxf(m, mn);
    float fct = __expf(m - mn);
    s *= fct; a0 *= fct; a1 *= fct;
    #pragma unroll
    for (int u = 0; u < 4; ++u){
      float w = __expf(p[u] - mn);
      float vx = __uint_as_float(vb[u] << 16);
      float vy = __uint_as_float(vb[u] & 0xFFFF0000u);
      s += w; a0 = fmaf(w, vx, a0); a1 = fmaf(w, vy, a1);
    }
    m = mn;
  }
  for (; e < end; ++e){
    const ushort_* r0 = kv + (size_t)csr_src[e]*2*HID + j;
    uint_ kb = *(const uint_*)r0;
    uint_ vb = *(const uint_*)(r0 + HID);
    float kx = __uint_as_float(kb << 16);
    float ky = __uint_as_float(kb & 0xFFFF0000u);
    float pp = kx*qv.x + ky*qv.y;
    pp += __shfl_xor(pp,1); pp += __shfl_xor(pp,2); pp += __shfl_xor(pp,4);
    float mn  = fmaxf(m, pp);
    float fct = __expf(m - mn);
    float w   = __expf(pp - mn);
    float vx = __uint_as_float(vb << 16);
    float vy = __uint_as_float(vb & 0xFFFF0000u);
    s  = s*fct + w;
    a0 = fmaf(w, vx, a0*fct);
    a1 = fmaf(w, vy, a1*fct);
    m = mn;
  }
  float inv = 1.f/(s + 1e-16f);
  *(float2*)(trans + (size_t)n*HID + j) =
      make_float2(gelu_tanh(a0*inv), gelu_tanh(a1*inv));
}

// ---- type-bucketed output GEMM (Wa) + fused epilogue -----------------------
__global__ void __launch_bounds__(256)
k_post_t(const float* __restrict__ trans, const float* __restrict__ xnorm,
         const int* __restrict__ tnodes, const int* __restrict__ tcount,
         const int* __restrict__ toffset, const float* __restrict__ Wpos,
         const float* __restrict__ Wa, const float* __restrict__ skip,
         const float* __restrict__ wpri,
         const float* __restrict__ hsrc, const float* __restrict__ csrc,
         float* __restrict__ hdst, float* __restrict__ cdst,
         float* __restrict__ pri, int last){
  int ty   = blockIdx.x / PROJ_BLOCKS_PER_TYPE;
  int tile = blockIdx.x % PROJ_BLOCKS_PER_TYPE;
  int cnt  = tcount[ty];
  int base = tile*TILE_N;
  if (base >= cnt) return;
  __shared__ float ts[TILE_N][HID];
  __shared__ int nl[TILE_N];
  int t  = threadIdx.x;
  int c  = t & 31;
  int rt = t >> 5;
  int off = toffset[ty];
  #pragma unroll
  for (int pass = 0; pass < 8; ++pass){
    int r = pass*8 + rt;
    int node = -1;
    float4 tv = make_float4(0.f,0.f,0.f,0.f);
    if (base + r < cnt){
      node = tnodes[off + base + r];
      tv = *(const float4*)(trans + (size_t)node*HID + 4*c);
    }
    if (c == 0) nl[r] = node;
    *(float4*)&ts[r][4*c] = tv;
  }
  __syncthreads();

  const float* W = Wa + (size_t)ty*HID*HID;
  float4 acc[8];
  #pragma unroll
  for (int r = 0; r < 8; ++r) acc[r] = make_float4(0.f,0.f,0.f,0.f);
  for (int k0 = 0; k0 < HID; k0 += 4){
    float4 hr[8];
    #pragma unroll
    for (int r = 0; r < 8; ++r) hr[r] = *(const float4*)&ts[rt*8+r][k0];
    #pragma unroll
    for (int kk = 0; kk < 4; ++kk){
      float4 w = *(const float4*)(W + (size_t)(k0+kk)*HID + 4*c);
      #pragma unroll
      for (int r = 0; r < 8; ++r){
        float hvv = ((const float*)&hr[r])[kk];
        acc[r].x = fmaf(hvv, w.x, acc[r].x);
        acc[r].y = fmaf(hvv, w.y, acc[r].y);
        acc[r].z = fmaf(hvv, w.z, acc[r].z);
        acc[r].w = fmaf(hvv, w.w, acc[r].w);
      }
    }
  }

  float sk = sigmoidf_(skip[ty]);
  float4 w0 = *(const float4*)(Wpos + 4*c);
  float4 w1 = *(const float4*)(Wpos + HID + 4*c);
  float4 wp = *(const float4*)(wpri + 4*c);
  float ppv[8];
  #pragma unroll
  for (int r = 0; r < 8; ++r){
    int node = nl[rt*8+r];
    ppv[r] = 0.f;
    if (node < 0) continue;
    size_t o = (size_t)node*HID + 4*c;
    float xa0 = xnorm[2*node], xa1 = xnorm[2*node+1];
    float4 hd = *(const float4*)(hsrc + o);
    float4 cv = *(const float4*)(csrc + o);
    float h0 = hd.x + xa0*w0.x + xa1*w1.x;
    float h1 = hd.y + xa0*w0.y + xa1*w1.y;
    float h2 = hd.z + xa0*w0.z + xa1*w1.z;
    float h3 = hd.w + xa0*w0.w + xa1*w1.w;
    float hg0 = sk*acc[r].x + (1.f - sk)*h0;
    float hg1 = sk*acc[r].y + (1.f - sk)*h1;
    float hg2 = sk*acc[r].z + (1.f - sk)*h2;
    float hg3 = sk*acc[r].w + (1.f - sk)*h3;
    ppv[r] = hg0*wp.x + hg1*wp.y + hg2*wp.z + hg3*wp.w;
    float c0 = hg0 + cv.x, c1 = hg1 + cv.y, c2 = hg2 + cv.z, c3 = hg3 + cv.w;
    *(float4*)(cdst + o) = make_float4(c0, c1, c2, c3);
    *(float4*)(hdst + o) = make_float4(hd.x + tanhf(c0), hd.y + tanhf(c1),
                                       hd.z + tanhf(c2), hd.w + tanhf(c3));
  }
  if (last){
    #pragma unroll
    for (int r = 0; r < 8; ++r){
      float pp = ppv[r];
      pp += __shfl_xor(pp, 1); pp += __shfl_xor(pp, 2); pp += __shfl_xor(pp, 4);
      pp += __shfl_xor(pp, 8); pp += __shfl_xor(pp, 16);
      ppv[r] = pp;
    }
    if (c == 0){
      #pragma unroll
      for (int r = 0; r < 8; ++r){
        int node = nl[rt*8+r];
        if (node >= 0) pri[node] = sigmoidf_(ppv[r]);
      }
    }
  }
}

// ---- launcher ---------------------------------------------------------------
extern "C" void kernel_launch(void* const* d_in, const int* in_sizes, int n_in,
                              void* d_out, int out_size, void* d_ws, size_t ws_size,
                              hipStream_t stream){
  const float* hidden_in = (const float*)d_in[0];
  const float* cn_in     = (const float*)d_in[1];
  const float* xnorm     = (const float*)d_in[2];
  const int*   ntype     = (const int*)d_in[3];
  const int*   esrc      = (const int*)d_in[4];
  const int*   edst      = (const int*)d_in[5];
  const float* Wpos      = (const float*)d_in[6];
  const float* Wk        = (const float*)d_in[7];
  const float* Wq        = (const float*)d_in[8];
  const float* Wv        = (const float*)d_in[9];
  const float* Wa        = (const float*)d_in[10];
  const float* Ratt      = (const float*)d_in[11];
  const float* Rmsg      = (const float*)d_in[12];
  const float* Rpri      = (const float*)d_in[13];
  const float* Skip      = (const float*)d_in[14];
  const float* Wpri      = (const float*)d_in[15];

  char* ws = (char*)d_ws;
  size_t off = 0;
  auto alloc = [&](size_t bytes)->void*{ void* p = ws + off; off += (bytes + 255) & ~(size_t)255; return p; };
  float*   qbuf  = (float*)alloc((size_t)N_NODES*HID*4);      // q, then trans (aliased)
  ushort_* kvbuf = (ushort_*)alloc((size_t)N_NODES*2*HID*2);  // bf16 kA | vm
  float* WkA   = (float*)alloc((size_t)NTYPE*HID*HID*4);
  float* WvM   = (float*)alloc((size_t)NTYPE*HID*HID*4);
  int* deg     = (int*)alloc((size_t)N_NODES*4);
  int* rowptr  = (int*)alloc((size_t)(N_NODES+1)*4);
  int* cursor  = (int*)alloc((size_t)N_NODES*4);
  int* csr     = (int*)alloc((size_t)N_EDGES*4);
  int* tcount  = (int*)alloc(8*4);
  int* toffset = (int*)alloc(8*4);
  int* tcursor = (int*)alloc(8*4);
  int* tnodes  = (int*)alloc((size_t)N_NODES*4);

  float* out_hidden = (float*)d_out;
  float* out_cn     = out_hidden + (size_t)N_NODES*HID;
  float* out_pri    = out_cn     + (size_t)N_NODES*HID;

  hipMemsetAsync(deg,     0, (size_t)N_NODES*4, stream);
  hipMemsetAsync(cursor,  0, (size_t)N_NODES*4, stream);
  hipMemsetAsync(tcount,  0, 8*4, stream);
  hipMemsetAsync(tcursor, 0, 8*4, stream);
  k_hist<<<(N_EDGES+255)/256, 256, 0, stream>>>(edst, deg);
  k_scan<<<1, 1024, 0, stream>>>(deg, rowptr);
  k_fill<<<(N_EDGES+255)/256, 256, 0, stream>>>(esrc, edst, rowptr, cursor, csr);
  k_thist<<<(N_NODES+255)/256, 256, 0, stream>>>(ntype, tcount);
  k_tscan<<<1, 64, 0, stream>>>(tcount, toffset);
  k_tfill<<<(N_NODES+255)/256, 256, 0, stream>>>(ntype, toffset, tcursor, tnodes);

  const int proj_grid = 3 * NTYPE * PROJ_BLOCKS_PER_TYPE;
  const int post_grid = NTYPE * PROJ_BLOCKS_PER_TYPE;
  for (int l = 0; l < NLAYER; ++l){
    const float* Wpos_l = Wpos + (size_t)l*2*HID;
    const float* Wq_l   = Wq   + (size_t)l*NTYPE*HID*HID;
    const float* Wk_l   = Wk   + (size_t)l*NTYPE*HID*HID;
    const float* Wv_l   = Wv   + (size_t)l*NTYPE*HID*HID;
    const float* Wa_l   = Wa   + (size_t)l*NTYPE*HID*HID;
    const float* Ratt_l = Ratt + (size_t)l*NHEAD*HDIM*HDIM;
    const float* Rmsg_l = Rmsg + (size_t)l*NHEAD*HDIM*HDIM;
    const float* Rpri_l = Rpri + (size_t)l*NHEAD;
    const float* Skip_l = Skip + (size_t)l*NTYPE;
    const float* Wpri_l = Wpri + (size_t)l*HID;

    const float* hsrc = (l == 0) ? hidden_in : out_hidden;
    const float* csrc = (l == 0) ? cn_in     : out_cn;

    k_effw<<<(NTYPE*HID*HID+255)/256, 256, 0, stream>>>(Wk_l, Wv_l, Ratt_l, Rmsg_l, Rpri_l, WkA, WvM);
    k_proj_t<<<proj_grid, 256, 0, stream>>>(hsrc, xnorm, tnodes, tcount, toffset,
                                            Wpos_l, Wq_l, WkA, WvM, qbuf, kvbuf);
    k_edge<<<N_NODES/4, 256, 0, stream>>>(rowptr, csr, qbuf, kvbuf, qbuf);
    k_post_t<<<post_grid, 256, 0, stream>>>(qbuf, xnorm, tnodes, tcount, toffset,
                                            Wpos_l, Wa_l, Skip_l, Wpri_l,
                                            hsrc, csrc, out_hidden, out_cn,
                                            out_pri, l == NLAYER-1);
  }
}

// Round 10
// 602.759 us; speedup vs baseline: 3.2410x; 1.1213x over previous
//
#include <hip/hip_runtime.h>
#include <hip/hip_bf16.h>
#include <math.h>

#define N_NODES 50000
#define N_EDGES 800000
#define HID     128
#define NHEAD   8
#define HDIM    16
#define NTYPE   6
#define NLAYER  2
#define PBT     782   // 64-node tiles per type, worst case

typedef unsigned int uint_;
typedef unsigned short ushort_;
typedef __attribute__((ext_vector_type(4))) float f32x4;
typedef __attribute__((ext_vector_type(8))) short short8;

__device__ __forceinline__ float sigmoidf_(float x){ return 1.f/(1.f+__expf(-x)); }
__device__ __forceinline__ float gelu_tanh(float x){
  float x3 = x*x*x;
  return 0.5f*x*(1.f + tanhf(0.7978845608028654f*(x + 0.044715f*x3)));
}
__device__ __forceinline__ ushort_ bf16r(float x){
  union{float f; uint_ u;} v; v.f = x;
  return (ushort_)((v.u + 0x7FFFu + ((v.u >> 16) & 1u)) >> 16);
}

// ---- CSR build --------------------------------------------------------------
__global__ void k_hist(const int* __restrict__ edst, int* __restrict__ deg){
  int e = blockIdx.x*256 + threadIdx.x;
  if (e < N_EDGES) atomicAdd(&deg[edst[e]], 1);
}

__global__ void __launch_bounds__(1024)
k_scan(const int* __restrict__ deg, int* __restrict__ rowptr){
  __shared__ int part[1024];
  const int chunk = (N_NODES + 1023)/1024;
  int t = threadIdx.x;
  int beg = t*chunk, end = min(beg+chunk, N_NODES);
  int s = 0;
  for (int i = beg; i < end; ++i) s += deg[i];
  part[t] = s;
  __syncthreads();
  if (t == 0){
    int acc = 0;
    for (int i = 0; i < 1024; ++i){ int v = part[i]; part[i] = acc; acc += v; }
    rowptr[N_NODES] = acc;
  }
  __syncthreads();
  int acc = part[t];
  for (int i = beg; i < end; ++i){ rowptr[i] = acc; acc += deg[i]; }
}

__global__ void k_fill(const int* __restrict__ esrc, const int* __restrict__ edst,
                       const int* __restrict__ rowptr, int* __restrict__ cursor,
                       int* __restrict__ csr_src){
  int e = blockIdx.x*256 + threadIdx.x;
  if (e < N_EDGES){
    int d = edst[e];
    int pos = atomicAdd(&cursor[d], 1);
    csr_src[rowptr[d] + pos] = esrc[e];
  }
}

// ---- type bucketing (block-aggregated) -------------------------------------
__global__ void k_thist(const int* __restrict__ ntype, int* __restrict__ tcount){
  __shared__ int c[NTYPE];
  int t = threadIdx.x;
  if (t < NTYPE) c[t] = 0;
  __syncthreads();
  int n = blockIdx.x*256 + t;
  if (n < N_NODES) atomicAdd(&c[ntype[n]], 1);
  __syncthreads();
  if (t < NTYPE && c[t] > 0) atomicAdd(&tcount[t], c[t]);
}

__global__ void k_tscan(const int* __restrict__ tcount, int* __restrict__ toffset){
  if (threadIdx.x == 0){
    int acc = 0;
    for (int i = 0; i < NTYPE; ++i){ toffset[i] = acc; acc += tcount[i]; }
  }
}

__global__ void k_tfill(const int* __restrict__ ntype, const int* __restrict__ toffset,
                        int* __restrict__ tcursor, int* __restrict__ tnodes){
  __shared__ int c[NTYPE], base[NTYPE];
  int t = threadIdx.x;
  if (t < NTYPE) c[t] = 0;
  __syncthreads();
  int n = blockIdx.x*256 + t;
  int ty = 0, rank = 0;
  bool valid = (n < N_NODES);
  if (valid){ ty = ntype[n]; rank = atomicAdd(&c[ty], 1); }
  __syncthreads();
  if (t < NTYPE && c[t] > 0) base[t] = atomicAdd(&tcursor[t], c[t]);
  __syncthreads();
  if (valid) tnodes[toffset[ty] + base[ty] + rank] = n;
}

// ---- pack effective weights into MFMA B-fragment order (bf16) --------------
// wpk layout: uint4[ ((t*4 + m)*32 + ks*8 + ct)*64 + lane ]
//   m: 0=Wq, 1=Wk*Ratt*pri/4, 2=Wv*Rmsg, 3=Wa
//   lane holds W[ks*32 + (lane>>4)*8 + j][ct*16 + (lane&15)], j=0..7
__global__ void k_packw(const float* __restrict__ Wq, const float* __restrict__ Wk,
                        const float* __restrict__ Wv, const float* __restrict__ Wa,
                        const float* __restrict__ A,  const float* __restrict__ M,
                        const float* __restrict__ pri, uint4* __restrict__ wpk){
  int idx = blockIdx.x*256 + threadIdx.x;        // 6*4*4*8*64 = 49152
  if (idx >= NTYPE*4*4*8*64) return;
  int l  = idx & 63;
  int ct = (idx >> 6) & 7;
  int ks = (idx >> 9) & 3;
  int m  = (idx >> 11) & 3;
  int t  = idx >> 13;
  int kbase = ks*32 + (l >> 4)*8;
  int c15 = l & 15;
  ushort_ out[8];
  if (m == 0 || m == 3){
    const float* W = (m == 0 ? Wq : Wa) + (size_t)t*HID*HID;
    int col = ct*16 + c15;
    #pragma unroll
    for (int j = 0; j < 8; ++j) out[j] = bf16r(W[(size_t)(kbase+j)*HID + col]);
  } else {
    const float* W = (m == 1 ? Wk : Wv) + (size_t)t*HID*HID;
    const float* R = (m == 1 ? A : M) + ct*HDIM*HDIM;
    float scale = (m == 1) ? pri[ct]*0.25f : 1.f;
    #pragma unroll
    for (int j = 0; j < 8; ++j){
      const float* wrow = W + (size_t)(kbase+j)*HID + ct*16;
      float s = 0.f;
      #pragma unroll
      for (int d = 0; d < HDIM; ++d) s += wrow[d]*R[d*HDIM + c15];
      out[j] = bf16r(s*scale);
    }
  }
  uint4 pk;
  pk.x = (uint_)out[0] | ((uint_)out[1] << 16);
  pk.y = (uint_)out[2] | ((uint_)out[3] << 16);
  pk.z = (uint_)out[4] | ((uint_)out[5] << 16);
  pk.w = (uint_)out[6] | ((uint_)out[7] << 16);
  wpk[idx] = pk;
}

// ---- MFMA projection: per wave 16 nodes x 128 cols, 3 matrices -------------
__global__ void __launch_bounds__(256)
k_proj_t(const float* __restrict__ hsrc, const float* __restrict__ xnorm,
         const int* __restrict__ tnodes, const int* __restrict__ tcount,
         const int* __restrict__ toffset, const float* __restrict__ Wpos,
         const uint4* __restrict__ wpk, float* __restrict__ qout,
         ushort_* __restrict__ kvout){
  int ty   = blockIdx.x / PBT;
  int tile = blockIdx.x % PBT;
  int cnt  = tcount[ty];
  int wid  = threadIdx.x >> 6, l = threadIdx.x & 63;
  int rowbase = tile*64 + wid*16;
  if (rowbase >= cnt) return;                    // wave-uniform
  int off = toffset[ty];
  int l15 = l & 15, lk = l >> 4;

  // A-fragments: 16 gathered node rows, bf16-packed, reused across 3 matrices
  int nrowA = rowbase + l15;
  int nodeA = tnodes[off + (nrowA < cnt ? nrowA : 0)];
  float xa0 = xnorm[2*nodeA], xa1 = xnorm[2*nodeA+1];
  short8 afr[4];
  #pragma unroll
  for (int ks = 0; ks < 4; ++ks){
    int col = ks*32 + lk*8;
    float4 h0 = *(const float4*)(hsrc + (size_t)nodeA*HID + col);
    float4 h1 = *(const float4*)(hsrc + (size_t)nodeA*HID + col + 4);
    float4 p0 = *(const float4*)(Wpos + col);
    float4 p1 = *(const float4*)(Wpos + col + 4);
    float4 q0 = *(const float4*)(Wpos + HID + col);
    float4 q1 = *(const float4*)(Wpos + HID + col + 4);
    union{ ushort_ h[8]; short8 s; } ap;
    ap.h[0] = bf16r(h0.x + xa0*p0.x + xa1*q0.x);
    ap.h[1] = bf16r(h0.y + xa0*p0.y + xa1*q0.y);
    ap.h[2] = bf16r(h0.z + xa0*p0.z + xa1*q0.z);
    ap.h[3] = bf16r(h0.w + xa0*p0.w + xa1*q0.w);
    ap.h[4] = bf16r(h1.x + xa0*p1.x + xa1*q1.x);
    ap.h[5] = bf16r(h1.y + xa0*p1.y + xa1*q1.y);
    ap.h[6] = bf16r(h1.z + xa0*p1.z + xa1*q1.z);
    ap.h[7] = bf16r(h1.w + xa0*p1.w + xa1*q1.w);
    afr[ks] = ap.s;
  }

  // D-row -> node mapping (row = lk*4 + reg)
  int  ndw[4]; bool nvw[4];
  #pragma unroll
  for (int reg = 0; reg < 4; ++reg){
    int nr = rowbase + lk*4 + reg;
    nvw[reg] = (nr < cnt);
    ndw[reg] = tnodes[off + (nvw[reg] ? nr : 0)];
  }

  #pragma unroll 1
  for (int m = 0; m < 3; ++m){
    const uint4* wb = wpk + ((size_t)(ty*4 + m)*32)*64;
    #pragma unroll 1
    for (int ct = 0; ct < 8; ++ct){
      f32x4 acc = {0.f, 0.f, 0.f, 0.f};
      #pragma unroll
      for (int ks = 0; ks < 4; ++ks){
        union{ uint4 u; short8 s; } bw;
        bw.u = wb[(ks*8 + ct)*64 + l];
        acc = __builtin_amdgcn_mfma_f32_16x16x32_bf16(afr[ks], bw.s, acc, 0, 0, 0);
      }
      int colw = ct*16 + l15;
      #pragma unroll
      for (int reg = 0; reg < 4; ++reg){
        if (nvw[reg]){
          if (m == 0) qout[(size_t)ndw[reg]*HID + colw] = acc[reg];
          else kvout[(size_t)ndw[reg]*2*HID + (m == 2 ? HID : 0) + colw] = bf16r(acc[reg]);
        }
      }
    }
  }
}

// ---- edge attention: bf16 kv gather, online softmax, writes trans ----------
__global__ void k_edge(const int* __restrict__ rowptr, const int* __restrict__ csr_src,
                       const float* __restrict__ q, const ushort_* __restrict__ kv,
                       float* __restrict__ trans){
  int wid = threadIdx.x >> 6, lane = threadIdx.x & 63;
  int n = blockIdx.x*4 + wid;
  int j = 2*lane;
  int beg = rowptr[n], end = rowptr[n+1];
  float2 qv = *(const float2*)(q + (size_t)n*HID + j);
  float m = -INFINITY, s = 0.f, a0 = 0.f, a1 = 0.f;
  int e = beg;
  for (; e + 4 <= end; e += 4){
    uint_ kb[4], vb[4];
    float p[4];
    #pragma unroll
    for (int u = 0; u < 4; ++u){
      const ushort_* r0 = kv + (size_t)csr_src[e+u]*2*HID + j;
      kb[u] = *(const uint_*)r0;
      vb[u] = *(const uint_*)(r0 + HID);
    }
    #pragma unroll
    for (int u = 0; u < 4; ++u){
      float kx = __uint_as_float(kb[u] << 16);
      float ky = __uint_as_float(kb[u] & 0xFFFF0000u);
      float pp = kx*qv.x + ky*qv.y;
      pp += __shfl_xor(pp,1); pp += __shfl_xor(pp,2); pp += __shfl_xor(pp,4);
      p[u] = pp;
    }
    float mn = fmaxf(fmaxf(p[0],p[1]), fmaxf(p[2],p[3]));
    mn = fmaxf(m, mn);
    float fct = __expf(m - mn);
    s *= fct; a0 *= fct; a1 *= fct;
    #pragma unroll
    for (int u = 0; u < 4; ++u){
      float w = __expf(p[u] - mn);
      float vx = __uint_as_float(vb[u] << 16);
      float vy = __uint_as_float(vb[u] & 0xFFFF0000u);
      s += w; a0 = fmaf(w, vx, a0); a1 = fmaf(w, vy, a1);
    }
    m = mn;
  }
  for (; e < end; ++e){
    const ushort_* r0 = kv + (size_t)csr_src[e]*2*HID + j;
    uint_ kb = *(const uint_*)r0;
    uint_ vb = *(const uint_*)(r0 + HID);
    float kx = __uint_as_float(kb << 16);
    float ky = __uint_as_float(kb & 0xFFFF0000u);
    float pp = kx*qv.x + ky*qv.y;
    pp += __shfl_xor(pp,1); pp += __shfl_xor(pp,2); pp += __shfl_xor(pp,4);
    float mn  = fmaxf(m, pp);
    float fct = __expf(m - mn);
    float w   = __expf(pp - mn);
    float vx = __uint_as_float(vb << 16);
    float vy = __uint_as_float(vb & 0xFFFF0000u);
    s  = s*fct + w;
    a0 = fmaf(w, vx, a0*fct);
    a1 = fmaf(w, vy, a1*fct);
    m = mn;
  }
  float inv = 1.f/(s + 1e-16f);
  *(float2*)(trans + (size_t)n*HID + j) =
      make_float2(gelu_tanh(a0*inv), gelu_tanh(a1*inv));
}

// ---- MFMA output GEMM (Wa) + fused epilogue --------------------------------
__global__ void __launch_bounds__(256)
k_post_t(const float* __restrict__ trans, const float* __restrict__ xnorm,
         const int* __restrict__ tnodes, const int* __restrict__ tcount,
         const int* __restrict__ toffset, const float* __restrict__ Wpos,
         const uint4* __restrict__ wpk, const float* __restrict__ skip,
         const float* __restrict__ wpri,
         const float* __restrict__ hsrc, const float* __restrict__ csrc,
         float* __restrict__ hdst, float* __restrict__ cdst,
         float* __restrict__ pri, int last){
  int ty   = blockIdx.x / PBT;
  int tile = blockIdx.x % PBT;
  int cnt  = tcount[ty];
  int wid  = threadIdx.x >> 6, l = threadIdx.x & 63;
  int rowbase = tile*64 + wid*16;
  if (rowbase >= cnt) return;
  int off = toffset[ty];
  int l15 = l & 15, lk = l >> 4;

  // A-fragments from trans (gelu'd aggregate)
  int nrowA = rowbase + l15;
  int nodeA = tnodes[off + (nrowA < cnt ? nrowA : 0)];
  short8 afr[4];
  #pragma unroll
  for (int ks = 0; ks < 4; ++ks){
    int col = ks*32 + lk*8;
    float4 t0 = *(const float4*)(trans + (size_t)nodeA*HID + col);
    float4 t1 = *(const float4*)(trans + (size_t)nodeA*HID + col + 4);
    union{ ushort_ h[8]; short8 s; } ap;
    ap.h[0] = bf16r(t0.x); ap.h[1] = bf16r(t0.y);
    ap.h[2] = bf16r(t0.z); ap.h[3] = bf16r(t0.w);
    ap.h[4] = bf16r(t1.x); ap.h[5] = bf16r(t1.y);
    ap.h[6] = bf16r(t1.z); ap.h[7] = bf16r(t1.w);
    afr[ks] = ap.s;
  }

  const uint4* wb = wpk + ((size_t)(ty*4 + 3)*32)*64;   // m=3: Wa
  f32x4 accs[8];
  #pragma unroll 1
  for (int ct = 0; ct < 8; ++ct){
    f32x4 acc = {0.f, 0.f, 0.f, 0.f};
    #pragma unroll
    for (int ks = 0; ks < 4; ++ks){
      union{ uint4 u; short8 s; } bw;
      bw.u = wb[(ks*8 + ct)*64 + l];
      acc = __builtin_amdgcn_mfma_f32_16x16x32_bf16(afr[ks], bw.s, acc, 0, 0, 0);
    }
    accs[ct] = acc;
  }

  float sk = sigmoidf_(skip[ty]);
  #pragma unroll 1
  for (int reg = 0; reg < 4; ++reg){
    int nr = rowbase + lk*4 + reg;
    bool nv = (nr < cnt);
    int nd = tnodes[off + (nv ? nr : 0)];
    float xa0 = xnorm[2*nd], xa1 = xnorm[2*nd+1];
    float ppart = 0.f;
    #pragma unroll
    for (int ct = 0; ct < 8; ++ct){
      int col = ct*16 + l15;
      size_t o = (size_t)nd*HID + col;
      float w0 = Wpos[col], w1 = Wpos[HID + col];
      float hd = hsrc[o];
      float h  = hd + xa0*w0 + xa1*w1;
      float hg = sk*accs[ct][reg] + (1.f - sk)*h;
      if (last) ppart = fmaf(hg, wpri[col], ppart);
      float cnew = hg + csrc[o];
      if (nv){
        cdst[o] = cnew;
        hdst[o] = hd + tanhf(cnew);
      }
    }
    if (last){
      ppart += __shfl_xor(ppart, 1); ppart += __shfl_xor(ppart, 2);
      ppart += __shfl_xor(ppart, 4); ppart += __shfl_xor(ppart, 8);
      if (l15 == 0 && nv) pri[nd] = sigmoidf_(ppart);
    }
  }
}

// ---- launcher ---------------------------------------------------------------
extern "C" void kernel_launch(void* const* d_in, const int* in_sizes, int n_in,
                              void* d_out, int out_size, void* d_ws, size_t ws_size,
                              hipStream_t stream){
  const float* hidden_in = (const float*)d_in[0];
  const float* cn_in     = (const float*)d_in[1];
  const float* xnorm     = (const float*)d_in[2];
  const int*   ntype     = (const int*)d_in[3];
  const int*   esrc      = (const int*)d_in[4];
  const int*   edst      = (const int*)d_in[5];
  const float* Wpos      = (const float*)d_in[6];
  const float* Wk        = (const float*)d_in[7];
  const float* Wq        = (const float*)d_in[8];
  const float* Wv        = (const float*)d_in[9];
  const float* Wa        = (const float*)d_in[10];
  const float* Ratt      = (const float*)d_in[11];
  const float* Rmsg      = (const float*)d_in[12];
  const float* Rpri      = (const float*)d_in[13];
  const float* Skip      = (const float*)d_in[14];
  const float* Wpri      = (const float*)d_in[15];

  char* ws = (char*)d_ws;
  size_t off = 0;
  auto alloc = [&](size_t bytes)->void*{ void* p = ws + off; off += (bytes + 255) & ~(size_t)255; return p; };
  float*   qbuf  = (float*)alloc((size_t)N_NODES*HID*4);      // q, then trans (aliased)
  ushort_* kvbuf = (ushort_*)alloc((size_t)N_NODES*2*HID*2);  // bf16 kA | vm
  uint4*   wpk   = (uint4*)alloc((size_t)NTYPE*4*4*8*64*16);  // packed bf16 frags
  int* deg     = (int*)alloc((size_t)N_NODES*4);
  int* rowptr  = (int*)alloc((size_t)(N_NODES+1)*4);
  int* cursor  = (int*)alloc((size_t)N_NODES*4);
  int* csr     = (int*)alloc((size_t)N_EDGES*4);
  int* tcount  = (int*)alloc(8*4);
  int* toffset = (int*)alloc(8*4);
  int* tcursor = (int*)alloc(8*4);
  int* tnodes  = (int*)alloc((size_t)N_NODES*4);

  float* out_hidden = (float*)d_out;
  float* out_cn     = out_hidden + (size_t)N_NODES*HID;
  float* out_pri    = out_cn     + (size_t)N_NODES*HID;

  hipMemsetAsync(deg,     0, (size_t)N_NODES*4, stream);
  hipMemsetAsync(cursor,  0, (size_t)N_NODES*4, stream);
  hipMemsetAsync(tcount,  0, 8*4, stream);
  hipMemsetAsync(tcursor, 0, 8*4, stream);
  k_hist<<<(N_EDGES+255)/256, 256, 0, stream>>>(edst, deg);
  k_scan<<<1, 1024, 0, stream>>>(deg, rowptr);
  k_fill<<<(N_EDGES+255)/256, 256, 0, stream>>>(esrc, edst, rowptr, cursor, csr);
  k_thist<<<(N_NODES+255)/256, 256, 0, stream>>>(ntype, tcount);
  k_tscan<<<1, 64, 0, stream>>>(tcount, toffset);
  k_tfill<<<(N_NODES+255)/256, 256, 0, stream>>>(ntype, toffset, tcursor, tnodes);

  const int gemm_grid = NTYPE * PBT;
  for (int l = 0; l < NLAYER; ++l){
    const float* Wpos_l = Wpos + (size_t)l*2*HID;
    const float* Wq_l   = Wq   + (size_t)l*NTYPE*HID*HID;
    const float* Wk_l   = Wk   + (size_t)l*NTYPE*HID*HID;
    const float* Wv_l   = Wv   + (size_t)l*NTYPE*HID*HID;
    const float* Wa_l   = Wa   + (size_t)l*NTYPE*HID*HID;
    const float* Ratt_l = Ratt + (size_t)l*NHEAD*HDIM*HDIM;
    const float* Rmsg_l = Rmsg + (size_t)l*NHEAD*HDIM*HDIM;
    const float* Rpri_l = Rpri + (size_t)l*NHEAD;
    const float* Skip_l = Skip + (size_t)l*NTYPE;
    const float* Wpri_l = Wpri + (size_t)l*HID;

    const float* hsrc = (l == 0) ? hidden_in : out_hidden;
    const float* csrc = (l == 0) ? cn_in     : out_cn;

    k_packw<<<(NTYPE*4*4*8*64 + 255)/256, 256, 0, stream>>>(
        Wq_l, Wk_l, Wv_l, Wa_l, Ratt_l, Rmsg_l, Rpri_l, wpk);
    k_proj_t<<<gemm_grid, 256, 0, stream>>>(hsrc, xnorm, tnodes, tcount, toffset,
                                            Wpos_l, wpk, qbuf, kvbuf);
    k_edge<<<N_NODES/4, 256, 0, stream>>>(rowptr, csr, qbuf, kvbuf, qbuf);
    k_post_t<<<gemm_grid, 256, 0, stream>>>(qbuf, xnorm, tnodes, tcount, toffset,
                                            Wpos_l, wpk, Skip_l, Wpri_l,
                                            hsrc, csrc, out_hidden, out_cn,
                                            out_pri, l == NLAYER-1);
  }
}